// Round 8
// baseline (5130.867 us; speedup 1.0000x reference)
//
#include <hip/hip_runtime.h>

typedef unsigned int uint;
typedef unsigned short ushort;
using half8v  = __attribute__((ext_vector_type(8))) _Float16;
using half4v  = __attribute__((ext_vector_type(4))) _Float16;
using float4v = __attribute__((ext_vector_type(4))) float;

#define EPS_SINK 0.0025f
#define INV_EPS_SINK 400.0f
#define EPS_LOG512 0.015595811562598769f

// ---- workspace layout (BYTE offsets), peak ~165 MB ----
static const size_t O_W1HI = 0ull;             // 512*512*8 f16 = 4,194,304 B
static const size_t O_W1LO = 4194304ull;
static const size_t O_W2HI = 8388608ull;
static const size_t O_W2LO = 10485760ull;
static const size_t O_W3HI = 12582912ull;
static const size_t O_W3LO = 14680064ull;
static const size_t O_W4HI = 16777216ull;
static const size_t O_W4LO = 18874368ull;
static const size_t O_H0   = 20971520ull;      // 16*512*6400 f16 = 104,857,600 B
static const size_t O_H1   = 125829120ull;     // 16*256*1598 uint = 26,181,632 B
static const size_t O_H2   = 20971520ull;      // alias h0 (dead after conv1)
static const size_t O_H3   = 34045952ull;
static const size_t O_FEATX= 152010752ull;     // 16*512*198 fp32
static const size_t O_FEATY= 158498816ull;
static const size_t O_STATS= 164986880ull;     // 512 floats
// cost phase (weights/h0/h1 all dead).  C stored f16, value = 100*C:
static const size_t O_CXY  = 0ull;             // 8,388,608 B each
static const size_t O_CTXY = 8388608ull;
static const size_t O_CXX  = 16777216ull;
static const size_t O_CYY  = 25165824ull;
static const size_t O_AAX  = 33554432ull;
static const size_t O_AAY  = 33587200ull;
static const size_t O_PART = 33619968ull;      // 48 floats

// ---------------------------------------------------------------------------
// prep_w: split conv weights fp32 -> f16 hi/lo. W1 [oc][ic][8 taps];
// W2-4 pair-interleaved [oc][icpair][dt0 icA, dt0 icB, dt1 icA, ...].
// ---------------------------------------------------------------------------
__global__ __launch_bounds__(256) void prep_w(
    const float* __restrict__ W1, const float* __restrict__ W2,
    const float* __restrict__ W3, const float* __restrict__ W4,
    _Float16* __restrict__ w1hi, _Float16* __restrict__ w1lo,
    _Float16* __restrict__ w2hi, _Float16* __restrict__ w2lo,
    _Float16* __restrict__ w3hi, _Float16* __restrict__ w3lo,
    _Float16* __restrict__ w4hi, _Float16* __restrict__ w4lo)
{
    const int layer = blockIdx.y;
    const int e = blockIdx.x * 256 + threadIdx.x;
    float v[8];
    _Float16 *dh, *dl;
    if (layer == 0) {
        const float4 a = *(const float4*)(W1 + (size_t)e * 8);
        const float4 c = *(const float4*)(W1 + (size_t)e * 8 + 4);
        v[0]=a.x; v[1]=a.y; v[2]=a.z; v[3]=a.w; v[4]=c.x; v[5]=c.y; v[6]=c.z; v[7]=c.w;
        dh = w1hi; dl = w1lo;
    } else {
        if (e >= 131072) return;
        const float* W = (layer == 1) ? W2 : (layer == 2) ? W3 : W4;
        dh = (layer == 1) ? w2hi : (layer == 2) ? w3hi : w4hi;
        dl = (layer == 1) ? w2lo : (layer == 2) ? w3lo : w4lo;
        const int oc = e >> 8, icp = e & 255;
        const float4 a = *(const float4*)(W + ((size_t)oc * 512 + icp * 2) * 4);
        const float4 c = *(const float4*)(W + ((size_t)oc * 512 + icp * 2 + 1) * 4);
        v[0]=a.x; v[1]=c.x; v[2]=a.y; v[3]=c.y; v[4]=a.z; v[5]=c.z; v[6]=a.w; v[7]=c.w;
    }
    half8v hi, lo;
#pragma unroll
    for (int k = 0; k < 8; ++k) {
        const _Float16 h = (_Float16)v[k];
        hi[k] = h;
        lo[k] = (_Float16)(v[k] - (float)h);
    }
    *(half8v*)(dh + (size_t)e * 8) = hi;
    *(half8v*)(dl + (size_t)e * 8) = lo;
}

// ---------------------------------------------------------------------------
// conv0_store: raw conv0 (k=10,s=5) -> h0 f16 [b][512][6400] + GN stats.
// ---------------------------------------------------------------------------
__global__ __launch_bounds__(256) void conv0_store(
    const float* __restrict__ wav, const float* __restrict__ W0,
    _Float16* __restrict__ h0, float* __restrict__ stats)
{
    __shared__ float LW[5120];
    __shared__ float red[2][256];
    const int tid = threadIdx.x;
    for (int e = tid; e < 5120; e += 256) LW[e] = W0[e];

    const int b = blockIdx.y;
    const int t = blockIdx.x * 256 + tid;
    const bool valid = (t < 6399);
    float xv[10];
#pragma unroll
    for (int d = 0; d < 10; ++d) xv[d] = 0.f;
    if (valid) {
        const float* wp = wav + (size_t)b * 32000 + (size_t)t * 5;
#pragma unroll
        for (int d = 0; d < 10; ++d) xv[d] = wp[d];
    }
    __syncthreads();

    float lsum = 0.f, lsq = 0.f;
    _Float16* hb = h0 + (size_t)b * 512 * 6400;
    for (int oc = 0; oc < 512; ++oc) {
        float a = 0.f;
#pragma unroll
        for (int d = 0; d < 10; ++d) a += LW[oc * 10 + d] * xv[d];
        if (valid) {
            hb[(size_t)oc * 6400 + t] = (_Float16)a;
            lsum += a; lsq += a * a;
        }
    }
    red[0][tid] = lsum; red[1][tid] = lsq;
    __syncthreads();
    for (int s2 = 128; s2 > 0; s2 >>= 1) {
        if (tid < s2) { red[0][tid] += red[0][tid + s2]; red[1][tid] += red[1][tid + s2]; }
        __syncthreads();
    }
    if (tid == 0) {
        atomicAdd(&stats[2 * b], red[0][0]);
        atomicAdd(&stats[2 * b + 1], red[1][0]);
    }
}

// ---------------------------------------------------------------------------
// norm_h0: in-place GN0 + affine + ReLU on h0 f16; zeroes tail slot 6399.
// ---------------------------------------------------------------------------
__global__ __launch_bounds__(256) void norm_h0(
    _Float16* __restrict__ h0, const float* __restrict__ stats,
    const float* __restrict__ gamma, const float* __restrict__ beta)
{
    const int row = blockIdx.y;
    const int b = row >> 9, oc = row & 511;
    const int t8 = (blockIdx.x * 256 + threadIdx.x) * 8;
    if (t8 >= 6400) return;
    const float invN = 1.f / (512.f * 6399.f);
    const float mu = stats[2 * b] * invN;
    const float var = stats[2 * b + 1] * invN - mu * mu;
    const float rs = rsqrtf(var + 1e-5f);
    const float sc = rs * gamma[oc];
    const float sh = beta[oc] - mu * sc;
    _Float16* p = h0 + (size_t)row * 6400 + t8;
    half8v v = *(half8v*)p;
#pragma unroll
    for (int k = 0; k < 8; ++k) {
        const float f = (t8 + k < 6399) ? fmaxf((float)v[k] * sc + sh, 0.f) : 0.f;
        v[k] = (_Float16)f;
    }
    *(half8v*)p = v;
}

// ---------------------------------------------------------------------------
// conv1_mfma: layer1 (K=8,S=4) from NORMALIZED h0. 128oc x 64t tile, 4 waves,
// each wave 4x2 MFMA tiles. W compensated hi/lo (2 MFMAs). Output f16
// pair-interleaved [b][256 pairs][1598][2] + GN1 stats.
// ---------------------------------------------------------------------------
__global__ __launch_bounds__(256) void conv1_mfma(
    const _Float16* __restrict__ h0,
    const _Float16* __restrict__ w1hi, const _Float16* __restrict__ w1lo,
    _Float16* __restrict__ oh, float* __restrict__ stats1)
{
    __shared__ _Float16 LWhi[2][128][40], LWlo[2][128][40];
    __shared__ _Float16 LX[8][272];
    __shared__ float red[2][256];

    const int tid  = threadIdx.x;
    const int lane = tid & 63, wv = tid >> 6;
    const int m    = lane & 15, quad = lane >> 4;
    const int wv2  = wv >> 1, wvt = wv & 1;
    const int b    = blockIdx.z;
    const int ocb  = blockIdx.y * 128;
    const int t0   = blockIdx.x * 64;
    const int Lout = 1598;

    float4v acc[4][2];
#pragma unroll
    for (int i = 0; i < 4; ++i)
#pragma unroll
        for (int j = 0; j < 2; ++j) acc[i][j] = (float4v){0.f, 0.f, 0.f, 0.f};

    const _Float16* hb = h0 + (size_t)b * 512 * 6400;
    const int gbase = t0 * 4;
    const int lim = 6400 - gbase;   // valid f16s in padded row from gbase

    for (int ic0 = 0; ic0 < 512; ic0 += 8) {
        __syncthreads();
        // --- stage W: 1024 frag-units (k32l, oc, q)
#pragma unroll
        for (int r = 0; r < 4; ++r) {
            const int e = tid + r * 256;
            const int k32l = e >> 9, oc = (e >> 2) & 127, q = e & 3;
            const size_t so = ((size_t)(ocb + oc) * 512 + ic0 + k32l * 4 + q) * 8;
            *(half8v*)&LWhi[k32l][oc][q * 8] = *(const half8v*)(w1hi + so);
            *(half8v*)&LWlo[k32l][oc][q * 8] = *(const half8v*)(w1lo + so);
        }
        // --- stage X: pure copy (272 16B-units; h0 already normalized)
        for (int e = tid; e < 272; e += 256) {
            const int ic = e / 34, u = e - ic * 34;
            const _Float16* src = hb + (size_t)(ic0 + ic) * 6400 + gbase + u * 8;
            half8v val;
            if (u * 8 + 7 < lim) val = *(const half8v*)src;
            else {
#pragma unroll
                for (int k = 0; k < 8; ++k) val[k] = (u * 8 + k < lim) ? src[k] : (_Float16)0.f;
            }
            *(half8v*)&LX[ic][u * 8] = val;
        }
        __syncthreads();
        // --- compute: 2 K-steps of 32
#pragma unroll
        for (int k32l = 0; k32l < 2; ++k32l) {
            half8v ahi[4], alo[4], bf[2];
#pragma unroll
            for (int i = 0; i < 4; ++i) {
                const int ocl = wv2 * 64 + i * 16 + m;
                ahi[i] = *(const half8v*)&LWhi[k32l][ocl][quad * 8];
                alo[i] = *(const half8v*)&LWlo[k32l][ocl][quad * 8];
            }
#pragma unroll
            for (int j = 0; j < 2; ++j) {
                const int tl = wvt * 32 + j * 16 + m;
                const int icl = k32l * 4 + quad;
                const half4v x0 = *(const half4v*)&LX[icl][tl * 4];
                const half4v x1 = *(const half4v*)&LX[icl][tl * 4 + 4];
                bf[j] = __builtin_shufflevector(x0, x1, 0, 1, 2, 3, 4, 5, 6, 7);
            }
#pragma unroll
            for (int i = 0; i < 4; ++i)
#pragma unroll
                for (int j = 0; j < 2; ++j) {
                    acc[i][j] = __builtin_amdgcn_mfma_f32_16x16x32_f16(ahi[i], bf[j], acc[i][j], 0, 0, 0);
                    acc[i][j] = __builtin_amdgcn_mfma_f32_16x16x32_f16(alo[i], bf[j], acc[i][j], 0, 0, 0);
                }
        }
    }

    // --- epilogue: pack f16 pairs + stats
    float lsum = 0.f, lsq = 0.f;
    uint* ohU = (uint*)oh;
#pragma unroll
    for (int i = 0; i < 4; ++i) {
        const int ocb2 = ocb + wv2 * 64 + i * 16 + quad * 4;
#pragma unroll
        for (int j = 0; j < 2; ++j) {
            const int t = t0 + wvt * 32 + j * 16 + m;
            if (t < Lout) {
#pragma unroll
                for (int pr = 0; pr < 2; ++pr) {
                    const float v0 = acc[i][j][pr * 2], v1 = acc[i][j][pr * 2 + 1];
                    union { uint u; _Float16 h[2]; } pk;
                    pk.h[0] = (_Float16)v0; pk.h[1] = (_Float16)v1;
                    const uint p = (uint)((ocb2 >> 1) + pr);
                    ohU[((size_t)(b * 256 + p)) * Lout + t] = pk.u;
                    lsum += v0 + v1; lsq += v0 * v0 + v1 * v1;
                }
            }
        }
    }
    __syncthreads();
    red[0][tid] = lsum; red[1][tid] = lsq;
    __syncthreads();
    for (int s2 = 128; s2 > 0; s2 >>= 1) {
        if (tid < s2) { red[0][tid] += red[0][tid + s2]; red[1][tid] += red[1][tid + s2]; }
        __syncthreads();
    }
    if (tid == 0) {
        atomicAdd(&stats1[2 * b], red[0][0]);
        atomicAdd(&stats1[2 * b + 1], red[1][0]);
    }
}

// ---------------------------------------------------------------------------
// conv_mfma: layers 2-4 (K=4,S=2). 128oc x 64t tile. Input pair-interleaved
// f16. PAIRED: f16 pair-interleaved out; else fp32 plain.
// ---------------------------------------------------------------------------
template <bool PAIRED>
__global__ __launch_bounds__(256) void conv_mfma(
    const _Float16* __restrict__ x,
    const _Float16* __restrict__ whi, const _Float16* __restrict__ wlo,
    _Float16* __restrict__ oh, float* __restrict__ oplain,
    float* __restrict__ stats, int Lin, int Lout)
{
    __shared__ _Float16 LWhi[2][128][40], LWlo[2][128][40];
    __shared__ _Float16 LX[8][272];
    __shared__ float red[2][256];

    const int tid  = threadIdx.x;
    const int lane = tid & 63, wv = tid >> 6;
    const int m    = lane & 15, quad = lane >> 4;
    const int wv2  = wv >> 1, wvt = wv & 1;
    const int b    = blockIdx.z;
    const int ocb  = blockIdx.y * 128;
    const int t0   = blockIdx.x * 64;

    float4v acc[4][2];
#pragma unroll
    for (int i = 0; i < 4; ++i)
#pragma unroll
        for (int j = 0; j < 2; ++j) acc[i][j] = (float4v){0.f, 0.f, 0.f, 0.f};

    const int lim = (Lin - t0 * 2) * 2;

    for (int ic0 = 0; ic0 < 512; ic0 += 16) {
        __syncthreads();
        // --- stage W: 1024 frag-units
#pragma unroll
        for (int r = 0; r < 4; ++r) {
            const int e = tid + r * 256;
            const int k32l = e >> 9, oc = (e >> 2) & 127, q = e & 3;
            const size_t so = ((size_t)(ocb + oc) * 256 + (ic0 >> 1) + k32l * 4 + q) * 8;
            *(half8v*)&LWhi[k32l][oc][q * 8] = *(const half8v*)(whi + so);
            *(half8v*)&LWlo[k32l][oc][q * 8] = *(const half8v*)(wlo + so);
        }
        // --- stage X (copy, 272 16B-units)
        for (int e = tid; e < 272; e += 256) {
            const int pl = e / 34, u = e - pl * 34;
            const _Float16* src = x + ((size_t)(b * 256 + (ic0 >> 1) + pl)) * ((size_t)Lin * 2)
                                   + (size_t)t0 * 4 + (size_t)u * 8;
            half8v val;
            if (u * 8 + 7 < lim) val = *(const half8v*)src;
            else {
#pragma unroll
                for (int k = 0; k < 8; ++k) val[k] = (u * 8 + k < lim) ? src[k] : (_Float16)0.f;
            }
            *(half8v*)&LX[pl][u * 8] = val;
        }
        __syncthreads();
        // --- compute
#pragma unroll
        for (int k32l = 0; k32l < 2; ++k32l) {
            half8v ahi[4], alo[4], bf[2];
#pragma unroll
            for (int i = 0; i < 4; ++i) {
                const int ocl = wv2 * 64 + i * 16 + m;
                ahi[i] = *(const half8v*)&LWhi[k32l][ocl][quad * 8];
                alo[i] = *(const half8v*)&LWlo[k32l][ocl][quad * 8];
            }
#pragma unroll
            for (int j = 0; j < 2; ++j) {
                const int tl = wvt * 32 + j * 16 + m;
                const int pl = k32l * 4 + quad;
                const half4v x0 = *(const half4v*)&LX[pl][tl * 4];
                const half4v x1 = *(const half4v*)&LX[pl][tl * 4 + 4];
                bf[j] = __builtin_shufflevector(x0, x1, 0, 1, 2, 3, 4, 5, 6, 7);
            }
#pragma unroll
            for (int i = 0; i < 4; ++i)
#pragma unroll
                for (int j = 0; j < 2; ++j) {
                    acc[i][j] = __builtin_amdgcn_mfma_f32_16x16x32_f16(ahi[i], bf[j], acc[i][j], 0, 0, 0);
                    acc[i][j] = __builtin_amdgcn_mfma_f32_16x16x32_f16(alo[i], bf[j], acc[i][j], 0, 0, 0);
                }
        }
    }

    // --- epilogue
    float lsum = 0.f, lsq = 0.f;
    uint* ohU = (uint*)oh;
#pragma unroll
    for (int i = 0; i < 4; ++i) {
        const int ocb2 = ocb + wv2 * 64 + i * 16 + quad * 4;
#pragma unroll
        for (int j = 0; j < 2; ++j) {
            const int t = t0 + wvt * 32 + j * 16 + m;
            if (t < Lout) {
                if (PAIRED) {
#pragma unroll
                    for (int pr = 0; pr < 2; ++pr) {
                        const float v0 = acc[i][j][pr * 2], v1 = acc[i][j][pr * 2 + 1];
                        union { uint u; _Float16 h[2]; } pk;
                        pk.h[0] = (_Float16)v0; pk.h[1] = (_Float16)v1;
                        const uint p = (uint)((ocb2 >> 1) + pr);
                        ohU[((size_t)(b * 256 + p)) * Lout + t] = pk.u;
                        lsum += v0 + v1; lsq += v0 * v0 + v1 * v1;
                    }
                } else {
#pragma unroll
                    for (int r = 0; r < 4; ++r) {
                        const float v = acc[i][j][r];
                        oplain[((size_t)(b * 512 + ocb2 + r)) * Lout + t] = v;
                        lsum += v; lsq += v * v;
                    }
                }
            }
        }
    }
    __syncthreads();
    red[0][tid] = lsum; red[1][tid] = lsq;
    __syncthreads();
    for (int s2 = 128; s2 > 0; s2 >>= 1) {
        if (tid < s2) { red[0][tid] += red[0][tid + s2]; red[1][tid] += red[1][tid + s2]; }
        __syncthreads();
    }
    if (tid == 0) {
        atomicAdd(&stats[2 * b], red[0][0]);
        atomicAdd(&stats[2 * b + 1], red[1][0]);
    }
}

// ---------------------------------------------------------------------------
// norm_pair: GN(1grp)+affine+ReLU in place on pair-interleaved f16.
// ---------------------------------------------------------------------------
__global__ __launch_bounds__(256) void norm_pair(
    uint* __restrict__ h, const float* __restrict__ stats,
    const float* __restrict__ gamma, const float* __restrict__ beta,
    int L, float invN)
{
    const int row = blockIdx.y;
    const int b = row >> 8, p = row & 255;
    const int t = blockIdx.x * 256 + threadIdx.x;
    if (t >= L) return;
    const int c0 = 2 * p, c1 = 2 * p + 1;
    const float mu = stats[2 * b] * invN;
    const float var = stats[2 * b + 1] * invN - mu * mu;
    const float rs = rsqrtf(var + 1e-5f);
    const float sc0 = rs * gamma[c0], sh0 = beta[c0] - mu * sc0;
    const float sc1 = rs * gamma[c1], sh1 = beta[c1] - mu * sc1;
    const size_t idx = (size_t)row * L + t;
    union { uint u; _Float16 h2[2]; } pk;
    pk.u = h[idx];
    const float n0 = fmaxf((float)pk.h2[0] * sc0 + sh0, 0.f);
    const float n1 = fmaxf((float)pk.h2[1] * sc1 + sh1, 0.f);
    pk.h2[0] = (_Float16)n0; pk.h2[1] = (_Float16)n1;
    h[idx] = pk.u;
}

// ---------------------------------------------------------------------------
// norm_feat: GN+affine+ReLU on plain fp32 features, in place.
// ---------------------------------------------------------------------------
__global__ __launch_bounds__(256) void norm_feat(
    float* __restrict__ h, const float* __restrict__ stats,
    const float* __restrict__ gamma, const float* __restrict__ beta,
    int L, float invN)
{
    const int row = blockIdx.y;
    const int b = row >> 9, oc = row & 511;
    const int t = blockIdx.x * 256 + threadIdx.x;
    if (t >= L) return;
    const float mu = stats[2 * b] * invN;
    const float var = stats[2 * b + 1] * invN - mu * mu;
    const float rs = rsqrtf(var + 1e-5f);
    const float sc = rs * gamma[oc];
    const float sh = beta[oc] - mu * sc;
    const size_t i = (size_t)row * L + t;
    const float v = h[i] * sc + sh;
    h[i] = v > 0.f ? v : 0.f;
}

// ---------------------------------------------------------------------------
// aa_kernel: row squared-norms of features.
// ---------------------------------------------------------------------------
__global__ __launch_bounds__(256) void aa_kernel(
    const float* __restrict__ fX, const float* __restrict__ fY,
    float* __restrict__ aaX, float* __restrict__ aaY)
{
    const int wave = threadIdx.x >> 6, lane = threadIdx.x & 63;
    const int R = blockIdx.x * 4 + wave;
    const float* f = (R < 8192) ? fX : fY;
    const int r = R & 8191;
    const float* row = f + (size_t)r * 198;
    float s = 0.f;
#pragma unroll
    for (int k = 0; k < 4; ++k) {
        const int j = lane + 64 * k;
        if (j < 198) { const float v = row[j]; s += v * v; }
    }
#pragma unroll
    for (int off = 32; off > 0; off >>= 1) s += __shfl_xor(s, off);
    if (lane == 0) ((R < 8192) ? aaX : aaY)[r] = s;
}

// ---------------------------------------------------------------------------
// cost_kernel: M = f16( min(50 * max(aa[n]+bb[m]-2<p,q>, 0), 65000) ) == 100*C
// ---------------------------------------------------------------------------
__global__ __launch_bounds__(256) void cost_kernel(
    const float* __restrict__ fX, const float* __restrict__ fY,
    const float* __restrict__ aaX, const float* __restrict__ aaY,
    _Float16* __restrict__ Cxy, _Float16* __restrict__ Cxx,
    _Float16* __restrict__ Cyy, _Float16* __restrict__ CTxy)
{
    const int z = blockIdx.z;
    const int mat = z >> 4, b = z & 15;
    const float *P, *Q, *aP, *aQ;
    _Float16 *Cm, *CT = nullptr;
    if (mat == 0) { P = fX; Q = fY; aP = aaX; aQ = aaY; Cm = Cxy; CT = CTxy; }
    else if (mat == 1) { P = fX; Q = fX; aP = aaX; aQ = aaX; Cm = Cxx; }
    else { P = fY; Q = fY; aP = aaY; aQ = aaY; Cm = Cyy; }

    const int n0 = blockIdx.x * 32, m0 = blockIdx.y * 32;
    __shared__ float LP[32][201], LQ[32][201];
    const int tid = threadIdx.x;
    for (int e = tid; e < 32 * 198; e += 256) {
        const int r = e / 198, d = e % 198;
        LP[r][d] = P[((size_t)b * 512 + n0 + r) * 198 + d];
        LQ[r][d] = Q[((size_t)b * 512 + m0 + r) * 198 + d];
    }
    __syncthreads();

    const int tx = tid & 31, ty = tid >> 5;
    float dot[4] = {0.f, 0.f, 0.f, 0.f};
    for (int d = 0; d < 198; ++d) {
        const float qv = LQ[tx][d];
#pragma unroll
        for (int q = 0; q < 4; ++q) dot[q] += LP[ty + 8 * q][d] * qv;
    }
    const int mm = m0 + tx;
    const float bbm = aQ[b * 512 + mm];
#pragma unroll
    for (int q = 0; q < 4; ++q) {
        const int n = n0 + ty + 8 * q;
        float c = 50.f * fmaxf(aP[b * 512 + n] + bbm - 2.f * dot[q], 0.f);  // == 100*C
        c = fminf(c, 65000.f);
        const _Float16 ch = (_Float16)c;
        Cm[((size_t)b * 512 + n) * 512 + mm] = ch;
        if (CT) CT[((size_t)b * 512 + mm) * 512 + n] = ch;
    }
}

// ---------------------------------------------------------------------------
// sinkhorn_all: ONE launch, 48 independent blocks (mat,b). f/g in LDS.
// 1024 threads = 16 waves; wave does 32 rows/half-update, 4 rows at a time.
// Math per row identical to round-7 sink_update (verified).
// part[z] = (sum(f)+sum(g))/512.
// ---------------------------------------------------------------------------
__global__ __launch_bounds__(1024) void sinkhorn_all(
    const _Float16* __restrict__ Cxy, const _Float16* __restrict__ CTxy,
    const _Float16* __restrict__ Cxx, const _Float16* __restrict__ Cyy,
    float* __restrict__ part)
{
    const int z = blockIdx.x;
    const int mat = z >> 4, b = z & 15;
    const _Float16 *Mf, *Mg;
    if (mat == 0) { Mf = Cxy; Mg = CTxy; }
    else if (mat == 1) { Mf = Cxx; Mg = Cxx; }
    else { Mf = Cyy; Mg = Cyy; }
    Mf += (size_t)b * 512 * 512;
    Mg += (size_t)b * 512 * 512;

    __shared__ float fv[512], gv[512];
    __shared__ float redp[16];
    const int tid = threadIdx.x;
    const int wave = tid >> 6, lane = tid & 63;
    if (tid < 512) fv[tid] = 0.f;
    __syncthreads();

    for (int it = 0; it < 50; ++it) {
#pragma unroll
        for (int half = 0; half < 2; ++half) {
            const float* srcv = (half == 0) ? fv : gv;
            float* dstv = (half == 0) ? gv : fv;
            const _Float16* M = (half == 0) ? Mg : Mf;
            float s8[8];
#pragma unroll
            for (int k = 0; k < 8; ++k) s8[k] = srcv[lane * 8 + k] * 400.f;
            for (int g4 = 0; g4 < 8; ++g4) {
                float mx4[4], ss4[4];
#pragma unroll
                for (int rr = 0; rr < 4; ++rr) {
                    const int row = wave * 32 + g4 * 4 + rr;
                    const half8v rv = *(const half8v*)(M + (size_t)row * 512 + lane * 8);
                    float a8[8];
#pragma unroll
                    for (int k = 0; k < 8; ++k) a8[k] = fmaf(-4.f, (float)rv[k], s8[k]);
                    float mx = fmaxf(fmaxf(fmaxf(a8[0], a8[1]), fmaxf(a8[2], a8[3])),
                                     fmaxf(fmaxf(a8[4], a8[5]), fmaxf(a8[6], a8[7])));
                    float ss = 0.f;
#pragma unroll
                    for (int k = 0; k < 8; ++k) ss += __expf(a8[k] - mx);
                    mx4[rr] = mx; ss4[rr] = ss;
                }
#pragma unroll
                for (int off = 32; off > 0; off >>= 1) {
#pragma unroll
                    for (int rr = 0; rr < 4; ++rr) {
                        const float om = __shfl_xor(mx4[rr], off);
                        const float os = __shfl_xor(ss4[rr], off);
                        const float nm = fmaxf(mx4[rr], om);
                        ss4[rr] = ss4[rr] * __expf(mx4[rr] - nm) + os * __expf(om - nm);
                        mx4[rr] = nm;
                    }
                }
                if (lane == 0) {
#pragma unroll
                    for (int rr = 0; rr < 4; ++rr)
                        dstv[wave * 32 + g4 * 4 + rr] =
                            EPS_LOG512 - EPS_SINK * (mx4[rr] + logf(ss4[rr]));
                }
            }
            __syncthreads();
        }
    }

    // partial = (sum f + sum g)/512
    float val = (tid < 512) ? fv[tid] : gv[tid - 512];
#pragma unroll
    for (int off = 32; off > 0; off >>= 1) val += __shfl_xor(val, off);
    if (lane == 0) redp[wave] = val;
    __syncthreads();
    if (tid == 0) {
        float tot = 0.f;
#pragma unroll
        for (int w = 0; w < 16; ++w) tot += redp[w];
        part[z] = tot * (1.0f / 512.0f);
    }
}

// ---------------------------------------------------------------------------
__global__ __launch_bounds__(64) void final2(
    const float* __restrict__ part, float* __restrict__ out)
{
    const int t = threadIdx.x;
    if (t < 16) out[t] = part[t] - 0.5f * (part[16 + t] + part[32 + t]);
}

// ---------------------------------------------------------------------------
extern "C" void kernel_launch(void* const* d_in, const int* in_sizes, int n_in,
                              void* d_out, int out_size, void* d_ws, size_t ws_size,
                              hipStream_t stream)
{
    (void)in_sizes; (void)n_in; (void)out_size; (void)ws_size;
    char* ws = (char*)d_ws;
    const float* yhat = (const float*)d_in[0];
    const float* ysig = (const float*)d_in[1];
    const float* Wl[5]; const float* gl[5]; const float* bl[5];
    for (int i = 0; i < 5; ++i) {
        Wl[i] = (const float*)d_in[2 + 3 * i];
        gl[i] = (const float*)d_in[3 + 3 * i];
        bl[i] = (const float*)d_in[4 + 3 * i];
    }
    float* out = (float*)d_out;
    float* statsA = (float*)(ws + O_STATS);

    _Float16* w1hi = (_Float16*)(ws + O_W1HI); _Float16* w1lo = (_Float16*)(ws + O_W1LO);
    _Float16* w2hi = (_Float16*)(ws + O_W2HI); _Float16* w2lo = (_Float16*)(ws + O_W2LO);
    _Float16* w3hi = (_Float16*)(ws + O_W3HI); _Float16* w3lo = (_Float16*)(ws + O_W3LO);
    _Float16* w4hi = (_Float16*)(ws + O_W4HI); _Float16* w4lo = (_Float16*)(ws + O_W4LO);
    _Float16* h0 = (_Float16*)(ws + O_H0);
    _Float16* h1 = (_Float16*)(ws + O_H1);
    _Float16* h2 = (_Float16*)(ws + O_H2);
    _Float16* h3 = (_Float16*)(ws + O_H3);

    hipMemsetAsync(statsA, 0, 512 * sizeof(float), stream);
    prep_w<<<dim3(1024, 4), 256, 0, stream>>>(Wl[1], Wl[2], Wl[3], Wl[4],
        w1hi, w1lo, w2hi, w2lo, w3hi, w3lo, w4hi, w4lo);

    for (int s = 0; s < 2; ++s) {
        const float* wav = (s == 0) ? yhat : ysig;
        float* st = statsA + (size_t)s * 160;
        float* ft = (float*)(ws + ((s == 0) ? O_FEATX : O_FEATY));

        conv0_store<<<dim3(25, 16), 256, 0, stream>>>(wav, Wl[0], h0, st);
        norm_h0<<<dim3(4, 8192), 256, 0, stream>>>(h0, st, gl[0], bl[0]);

        conv1_mfma<<<dim3(25, 4, 16), 256, 0, stream>>>(
            h0, w1hi, w1lo, h1, st + 32);
        norm_pair<<<dim3(7, 4096), 256, 0, stream>>>(
            (uint*)h1, st + 32, gl[1], bl[1], 1598, 1.f / (512.f * 1598.f));

        conv_mfma<true><<<dim3(13, 4, 16), 256, 0, stream>>>(
            h1, w2hi, w2lo, h2, nullptr, st + 64, 1598, 798);
        norm_pair<<<dim3(4, 4096), 256, 0, stream>>>(
            (uint*)h2, st + 64, gl[2], bl[2], 798, 1.f / (512.f * 798.f));

        conv_mfma<true><<<dim3(7, 4, 16), 256, 0, stream>>>(
            h2, w3hi, w3lo, h3, nullptr, st + 96, 798, 398);
        norm_pair<<<dim3(2, 4096), 256, 0, stream>>>(
            (uint*)h3, st + 96, gl[3], bl[3], 398, 1.f / (512.f * 398.f));

        conv_mfma<false><<<dim3(4, 4, 16), 256, 0, stream>>>(
            h3, w4hi, w4lo, nullptr, ft, st + 128, 398, 198);
        norm_feat<<<dim3(1, 8192), 256, 0, stream>>>(
            ft, st + 128, gl[4], bl[4], 198, 1.f / (512.f * 198.f));
    }

    float* featX = (float*)(ws + O_FEATX);
    float* featY = (float*)(ws + O_FEATY);
    aa_kernel<<<4096, 256, 0, stream>>>(featX, featY, (float*)(ws + O_AAX), (float*)(ws + O_AAY));
    cost_kernel<<<dim3(16, 16, 48), 256, 0, stream>>>(
        featX, featY, (float*)(ws + O_AAX), (float*)(ws + O_AAY),
        (_Float16*)(ws + O_CXY), (_Float16*)(ws + O_CXX), (_Float16*)(ws + O_CYY),
        (_Float16*)(ws + O_CTXY));

    sinkhorn_all<<<48, 1024, 0, stream>>>(
        (const _Float16*)(ws + O_CXY), (const _Float16*)(ws + O_CTXY),
        (const _Float16*)(ws + O_CXX), (const _Float16*)(ws + O_CYY),
        (float*)(ws + O_PART));

    final2<<<1, 64, 0, stream>>>((const float*)(ws + O_PART), out);
}

// Round 9
// 2722.775 us; speedup vs baseline: 1.8844x; 1.8844x over previous
//
#include <hip/hip_runtime.h>

typedef unsigned int uint;
typedef unsigned short ushort;
using half8v  = __attribute__((ext_vector_type(8))) _Float16;
using half4v  = __attribute__((ext_vector_type(4))) _Float16;
using float4v = __attribute__((ext_vector_type(4))) float;

#define EPS_SINK 0.0025f
#define INV_EPS_SINK 400.0f
#define EPS_LOG512 0.015595811562598769f

// ---- workspace layout (BYTE offsets), peak ~165 MB ----
static const size_t O_W1HI = 0ull;             // 512*512*8 f16 = 4,194,304 B
static const size_t O_W1LO = 4194304ull;
static const size_t O_W2HI = 8388608ull;
static const size_t O_W2LO = 10485760ull;
static const size_t O_W3HI = 12582912ull;
static const size_t O_W3LO = 14680064ull;
static const size_t O_W4HI = 16777216ull;
static const size_t O_W4LO = 18874368ull;
static const size_t O_H0   = 20971520ull;      // 16*512*6400 f16 = 104,857,600 B
static const size_t O_H1   = 125829120ull;     // 16*256*1598 uint = 26,181,632 B
static const size_t O_H2   = 20971520ull;      // alias h0 (dead after conv1)
static const size_t O_H3   = 34045952ull;
static const size_t O_FEATX= 152010752ull;     // 16*512*198 fp32
static const size_t O_FEATY= 158498816ull;
static const size_t O_STATS= 164986880ull;     // 512 floats
// cost phase (weights/h0/h1 all dead).  C stored f16, value = 100*C:
static const size_t O_CXY  = 0ull;             // 8,388,608 B each
static const size_t O_CTXY = 8388608ull;
static const size_t O_CXX  = 16777216ull;
static const size_t O_CYY  = 25165824ull;
static const size_t O_AAX  = 33554432ull;
static const size_t O_AAY  = 33587200ull;
static const size_t O_F    = 33619968ull;      // 3*16*512 fp32
static const size_t O_G    = 33718272ull;

// ---------------------------------------------------------------------------
// prep_w: split conv weights fp32 -> f16 hi/lo. W1 [oc][ic][8 taps];
// W2-4 pair-interleaved [oc][icpair][dt0 icA, dt0 icB, dt1 icA, ...].
// ---------------------------------------------------------------------------
__global__ __launch_bounds__(256) void prep_w(
    const float* __restrict__ W1, const float* __restrict__ W2,
    const float* __restrict__ W3, const float* __restrict__ W4,
    _Float16* __restrict__ w1hi, _Float16* __restrict__ w1lo,
    _Float16* __restrict__ w2hi, _Float16* __restrict__ w2lo,
    _Float16* __restrict__ w3hi, _Float16* __restrict__ w3lo,
    _Float16* __restrict__ w4hi, _Float16* __restrict__ w4lo)
{
    const int layer = blockIdx.y;
    const int e = blockIdx.x * 256 + threadIdx.x;
    float v[8];
    _Float16 *dh, *dl;
    if (layer == 0) {
        const float4 a = *(const float4*)(W1 + (size_t)e * 8);
        const float4 c = *(const float4*)(W1 + (size_t)e * 8 + 4);
        v[0]=a.x; v[1]=a.y; v[2]=a.z; v[3]=a.w; v[4]=c.x; v[5]=c.y; v[6]=c.z; v[7]=c.w;
        dh = w1hi; dl = w1lo;
    } else {
        if (e >= 131072) return;
        const float* W = (layer == 1) ? W2 : (layer == 2) ? W3 : W4;
        dh = (layer == 1) ? w2hi : (layer == 2) ? w3hi : w4hi;
        dl = (layer == 1) ? w2lo : (layer == 2) ? w3lo : w4lo;
        const int oc = e >> 8, icp = e & 255;
        const float4 a = *(const float4*)(W + ((size_t)oc * 512 + icp * 2) * 4);
        const float4 c = *(const float4*)(W + ((size_t)oc * 512 + icp * 2 + 1) * 4);
        v[0]=a.x; v[1]=c.x; v[2]=a.y; v[3]=c.y; v[4]=a.z; v[5]=c.z; v[6]=a.w; v[7]=c.w;
    }
    half8v hi, lo;
#pragma unroll
    for (int k = 0; k < 8; ++k) {
        const _Float16 h = (_Float16)v[k];
        hi[k] = h;
        lo[k] = (_Float16)(v[k] - (float)h);
    }
    *(half8v*)(dh + (size_t)e * 8) = hi;
    *(half8v*)(dl + (size_t)e * 8) = lo;
}

// ---------------------------------------------------------------------------
// conv0_store: raw conv0 (k=10,s=5) -> h0 f16 [b][512][6400] + GN stats.
// ---------------------------------------------------------------------------
__global__ __launch_bounds__(256) void conv0_store(
    const float* __restrict__ wav, const float* __restrict__ W0,
    _Float16* __restrict__ h0, float* __restrict__ stats)
{
    __shared__ float LW[5120];
    __shared__ float red[2][256];
    const int tid = threadIdx.x;
    for (int e = tid; e < 5120; e += 256) LW[e] = W0[e];

    const int b = blockIdx.y;
    const int t = blockIdx.x * 256 + tid;
    const bool valid = (t < 6399);
    float xv[10];
#pragma unroll
    for (int d = 0; d < 10; ++d) xv[d] = 0.f;
    if (valid) {
        const float* wp = wav + (size_t)b * 32000 + (size_t)t * 5;
#pragma unroll
        for (int d = 0; d < 10; ++d) xv[d] = wp[d];
    }
    __syncthreads();

    float lsum = 0.f, lsq = 0.f;
    _Float16* hb = h0 + (size_t)b * 512 * 6400;
    for (int oc = 0; oc < 512; ++oc) {
        float a = 0.f;
#pragma unroll
        for (int d = 0; d < 10; ++d) a += LW[oc * 10 + d] * xv[d];
        if (valid) {
            hb[(size_t)oc * 6400 + t] = (_Float16)a;
            lsum += a; lsq += a * a;
        }
    }
    red[0][tid] = lsum; red[1][tid] = lsq;
    __syncthreads();
    for (int s2 = 128; s2 > 0; s2 >>= 1) {
        if (tid < s2) { red[0][tid] += red[0][tid + s2]; red[1][tid] += red[1][tid + s2]; }
        __syncthreads();
    }
    if (tid == 0) {
        atomicAdd(&stats[2 * b], red[0][0]);
        atomicAdd(&stats[2 * b + 1], red[1][0]);
    }
}

// ---------------------------------------------------------------------------
// norm_h0: in-place GN0 + affine + ReLU on h0 f16; zeroes tail slot 6399.
// ---------------------------------------------------------------------------
__global__ __launch_bounds__(256) void norm_h0(
    _Float16* __restrict__ h0, const float* __restrict__ stats,
    const float* __restrict__ gamma, const float* __restrict__ beta)
{
    const int row = blockIdx.y;
    const int b = row >> 9, oc = row & 511;
    const int t8 = (blockIdx.x * 256 + threadIdx.x) * 8;
    if (t8 >= 6400) return;
    const float invN = 1.f / (512.f * 6399.f);
    const float mu = stats[2 * b] * invN;
    const float var = stats[2 * b + 1] * invN - mu * mu;
    const float rs = rsqrtf(var + 1e-5f);
    const float sc = rs * gamma[oc];
    const float sh = beta[oc] - mu * sc;
    _Float16* p = h0 + (size_t)row * 6400 + t8;
    half8v v = *(half8v*)p;
#pragma unroll
    for (int k = 0; k < 8; ++k) {
        const float f = (t8 + k < 6399) ? fmaxf((float)v[k] * sc + sh, 0.f) : 0.f;
        v[k] = (_Float16)f;
    }
    *(half8v*)p = v;
}

// ---------------------------------------------------------------------------
// conv1_mfma: layer1 (K=8,S=4) from NORMALIZED h0. 128oc x 64t tile, 4 waves,
// each wave 4x2 MFMA tiles. W compensated hi/lo (2 MFMAs). Output f16
// pair-interleaved [b][256 pairs][1598][2] + GN1 stats.
// ---------------------------------------------------------------------------
__global__ __launch_bounds__(256) void conv1_mfma(
    const _Float16* __restrict__ h0,
    const _Float16* __restrict__ w1hi, const _Float16* __restrict__ w1lo,
    _Float16* __restrict__ oh, float* __restrict__ stats1)
{
    __shared__ _Float16 LWhi[2][128][40], LWlo[2][128][40];
    __shared__ _Float16 LX[8][272];
    __shared__ float red[2][256];

    const int tid  = threadIdx.x;
    const int lane = tid & 63, wv = tid >> 6;
    const int m    = lane & 15, quad = lane >> 4;
    const int wv2  = wv >> 1, wvt = wv & 1;
    const int b    = blockIdx.z;
    const int ocb  = blockIdx.y * 128;
    const int t0   = blockIdx.x * 64;
    const int Lout = 1598;

    float4v acc[4][2];
#pragma unroll
    for (int i = 0; i < 4; ++i)
#pragma unroll
        for (int j = 0; j < 2; ++j) acc[i][j] = (float4v){0.f, 0.f, 0.f, 0.f};

    const _Float16* hb = h0 + (size_t)b * 512 * 6400;
    const int gbase = t0 * 4;
    const int lim = 6400 - gbase;   // valid f16s in padded row from gbase

    for (int ic0 = 0; ic0 < 512; ic0 += 8) {
        __syncthreads();
        // --- stage W: 1024 frag-units (k32l, oc, q)
#pragma unroll
        for (int r = 0; r < 4; ++r) {
            const int e = tid + r * 256;
            const int k32l = e >> 9, oc = (e >> 2) & 127, q = e & 3;
            const size_t so = ((size_t)(ocb + oc) * 512 + ic0 + k32l * 4 + q) * 8;
            *(half8v*)&LWhi[k32l][oc][q * 8] = *(const half8v*)(w1hi + so);
            *(half8v*)&LWlo[k32l][oc][q * 8] = *(const half8v*)(w1lo + so);
        }
        // --- stage X: pure copy (272 16B-units; h0 already normalized)
        for (int e = tid; e < 272; e += 256) {
            const int ic = e / 34, u = e - ic * 34;
            const _Float16* src = hb + (size_t)(ic0 + ic) * 6400 + gbase + u * 8;
            half8v val;
            if (u * 8 + 7 < lim) val = *(const half8v*)src;
            else {
#pragma unroll
                for (int k = 0; k < 8; ++k) val[k] = (u * 8 + k < lim) ? src[k] : (_Float16)0.f;
            }
            *(half8v*)&LX[ic][u * 8] = val;
        }
        __syncthreads();
        // --- compute: 2 K-steps of 32
#pragma unroll
        for (int k32l = 0; k32l < 2; ++k32l) {
            half8v ahi[4], alo[4], bf[2];
#pragma unroll
            for (int i = 0; i < 4; ++i) {
                const int ocl = wv2 * 64 + i * 16 + m;
                ahi[i] = *(const half8v*)&LWhi[k32l][ocl][quad * 8];
                alo[i] = *(const half8v*)&LWlo[k32l][ocl][quad * 8];
            }
#pragma unroll
            for (int j = 0; j < 2; ++j) {
                const int tl = wvt * 32 + j * 16 + m;
                const int icl = k32l * 4 + quad;
                const half4v x0 = *(const half4v*)&LX[icl][tl * 4];
                const half4v x1 = *(const half4v*)&LX[icl][tl * 4 + 4];
                bf[j] = __builtin_shufflevector(x0, x1, 0, 1, 2, 3, 4, 5, 6, 7);
            }
#pragma unroll
            for (int i = 0; i < 4; ++i)
#pragma unroll
                for (int j = 0; j < 2; ++j) {
                    acc[i][j] = __builtin_amdgcn_mfma_f32_16x16x32_f16(ahi[i], bf[j], acc[i][j], 0, 0, 0);
                    acc[i][j] = __builtin_amdgcn_mfma_f32_16x16x32_f16(alo[i], bf[j], acc[i][j], 0, 0, 0);
                }
        }
    }

    // --- epilogue: pack f16 pairs + stats
    float lsum = 0.f, lsq = 0.f;
    uint* ohU = (uint*)oh;
#pragma unroll
    for (int i = 0; i < 4; ++i) {
        const int ocb2 = ocb + wv2 * 64 + i * 16 + quad * 4;
#pragma unroll
        for (int j = 0; j < 2; ++j) {
            const int t = t0 + wvt * 32 + j * 16 + m;
            if (t < Lout) {
#pragma unroll
                for (int pr = 0; pr < 2; ++pr) {
                    const float v0 = acc[i][j][pr * 2], v1 = acc[i][j][pr * 2 + 1];
                    union { uint u; _Float16 h[2]; } pk;
                    pk.h[0] = (_Float16)v0; pk.h[1] = (_Float16)v1;
                    const uint p = (uint)((ocb2 >> 1) + pr);
                    ohU[((size_t)(b * 256 + p)) * Lout + t] = pk.u;
                    lsum += v0 + v1; lsq += v0 * v0 + v1 * v1;
                }
            }
        }
    }
    __syncthreads();
    red[0][tid] = lsum; red[1][tid] = lsq;
    __syncthreads();
    for (int s2 = 128; s2 > 0; s2 >>= 1) {
        if (tid < s2) { red[0][tid] += red[0][tid + s2]; red[1][tid] += red[1][tid + s2]; }
        __syncthreads();
    }
    if (tid == 0) {
        atomicAdd(&stats1[2 * b], red[0][0]);
        atomicAdd(&stats1[2 * b + 1], red[1][0]);
    }
}

// ---------------------------------------------------------------------------
// conv_mfma: layers 2-4 (K=4,S=2). 128oc x 64t tile. Input pair-interleaved
// f16. PAIRED: f16 pair-interleaved out; else fp32 plain.
// ---------------------------------------------------------------------------
template <bool PAIRED>
__global__ __launch_bounds__(256) void conv_mfma(
    const _Float16* __restrict__ x,
    const _Float16* __restrict__ whi, const _Float16* __restrict__ wlo,
    _Float16* __restrict__ oh, float* __restrict__ oplain,
    float* __restrict__ stats, int Lin, int Lout)
{
    __shared__ _Float16 LWhi[2][128][40], LWlo[2][128][40];
    __shared__ _Float16 LX[8][272];
    __shared__ float red[2][256];

    const int tid  = threadIdx.x;
    const int lane = tid & 63, wv = tid >> 6;
    const int m    = lane & 15, quad = lane >> 4;
    const int wv2  = wv >> 1, wvt = wv & 1;
    const int b    = blockIdx.z;
    const int ocb  = blockIdx.y * 128;
    const int t0   = blockIdx.x * 64;

    float4v acc[4][2];
#pragma unroll
    for (int i = 0; i < 4; ++i)
#pragma unroll
        for (int j = 0; j < 2; ++j) acc[i][j] = (float4v){0.f, 0.f, 0.f, 0.f};

    const int lim = (Lin - t0 * 2) * 2;

    for (int ic0 = 0; ic0 < 512; ic0 += 16) {
        __syncthreads();
        // --- stage W: 1024 frag-units
#pragma unroll
        for (int r = 0; r < 4; ++r) {
            const int e = tid + r * 256;
            const int k32l = e >> 9, oc = (e >> 2) & 127, q = e & 3;
            const size_t so = ((size_t)(ocb + oc) * 256 + (ic0 >> 1) + k32l * 4 + q) * 8;
            *(half8v*)&LWhi[k32l][oc][q * 8] = *(const half8v*)(whi + so);
            *(half8v*)&LWlo[k32l][oc][q * 8] = *(const half8v*)(wlo + so);
        }
        // --- stage X (copy, 272 16B-units)
        for (int e = tid; e < 272; e += 256) {
            const int pl = e / 34, u = e - pl * 34;
            const _Float16* src = x + ((size_t)(b * 256 + (ic0 >> 1) + pl)) * ((size_t)Lin * 2)
                                   + (size_t)t0 * 4 + (size_t)u * 8;
            half8v val;
            if (u * 8 + 7 < lim) val = *(const half8v*)src;
            else {
#pragma unroll
                for (int k = 0; k < 8; ++k) val[k] = (u * 8 + k < lim) ? src[k] : (_Float16)0.f;
            }
            *(half8v*)&LX[pl][u * 8] = val;
        }
        __syncthreads();
        // --- compute
#pragma unroll
        for (int k32l = 0; k32l < 2; ++k32l) {
            half8v ahi[4], alo[4], bf[2];
#pragma unroll
            for (int i = 0; i < 4; ++i) {
                const int ocl = wv2 * 64 + i * 16 + m;
                ahi[i] = *(const half8v*)&LWhi[k32l][ocl][quad * 8];
                alo[i] = *(const half8v*)&LWlo[k32l][ocl][quad * 8];
            }
#pragma unroll
            for (int j = 0; j < 2; ++j) {
                const int tl = wvt * 32 + j * 16 + m;
                const int pl = k32l * 4 + quad;
                const half4v x0 = *(const half4v*)&LX[pl][tl * 4];
                const half4v x1 = *(const half4v*)&LX[pl][tl * 4 + 4];
                bf[j] = __builtin_shufflevector(x0, x1, 0, 1, 2, 3, 4, 5, 6, 7);
            }
#pragma unroll
            for (int i = 0; i < 4; ++i)
#pragma unroll
                for (int j = 0; j < 2; ++j) {
                    acc[i][j] = __builtin_amdgcn_mfma_f32_16x16x32_f16(ahi[i], bf[j], acc[i][j], 0, 0, 0);
                    acc[i][j] = __builtin_amdgcn_mfma_f32_16x16x32_f16(alo[i], bf[j], acc[i][j], 0, 0, 0);
                }
        }
    }

    // --- epilogue
    float lsum = 0.f, lsq = 0.f;
    uint* ohU = (uint*)oh;
#pragma unroll
    for (int i = 0; i < 4; ++i) {
        const int ocb2 = ocb + wv2 * 64 + i * 16 + quad * 4;
#pragma unroll
        for (int j = 0; j < 2; ++j) {
            const int t = t0 + wvt * 32 + j * 16 + m;
            if (t < Lout) {
                if (PAIRED) {
#pragma unroll
                    for (int pr = 0; pr < 2; ++pr) {
                        const float v0 = acc[i][j][pr * 2], v1 = acc[i][j][pr * 2 + 1];
                        union { uint u; _Float16 h[2]; } pk;
                        pk.h[0] = (_Float16)v0; pk.h[1] = (_Float16)v1;
                        const uint p = (uint)((ocb2 >> 1) + pr);
                        ohU[((size_t)(b * 256 + p)) * Lout + t] = pk.u;
                        lsum += v0 + v1; lsq += v0 * v0 + v1 * v1;
                    }
                } else {
#pragma unroll
                    for (int r = 0; r < 4; ++r) {
                        const float v = acc[i][j][r];
                        oplain[((size_t)(b * 512 + ocb2 + r)) * Lout + t] = v;
                        lsum += v; lsq += v * v;
                    }
                }
            }
        }
    }
    __syncthreads();
    red[0][tid] = lsum; red[1][tid] = lsq;
    __syncthreads();
    for (int s2 = 128; s2 > 0; s2 >>= 1) {
        if (tid < s2) { red[0][tid] += red[0][tid + s2]; red[1][tid] += red[1][tid + s2]; }
        __syncthreads();
    }
    if (tid == 0) {
        atomicAdd(&stats[2 * b], red[0][0]);
        atomicAdd(&stats[2 * b + 1], red[1][0]);
    }
}

// ---------------------------------------------------------------------------
// norm_pair: GN(1grp)+affine+ReLU in place on pair-interleaved f16.
// ---------------------------------------------------------------------------
__global__ __launch_bounds__(256) void norm_pair(
    uint* __restrict__ h, const float* __restrict__ stats,
    const float* __restrict__ gamma, const float* __restrict__ beta,
    int L, float invN)
{
    const int row = blockIdx.y;
    const int b = row >> 8, p = row & 255;
    const int t = blockIdx.x * 256 + threadIdx.x;
    if (t >= L) return;
    const int c0 = 2 * p, c1 = 2 * p + 1;
    const float mu = stats[2 * b] * invN;
    const float var = stats[2 * b + 1] * invN - mu * mu;
    const float rs = rsqrtf(var + 1e-5f);
    const float sc0 = rs * gamma[c0], sh0 = beta[c0] - mu * sc0;
    const float sc1 = rs * gamma[c1], sh1 = beta[c1] - mu * sc1;
    const size_t idx = (size_t)row * L + t;
    union { uint u; _Float16 h2[2]; } pk;
    pk.u = h[idx];
    const float n0 = fmaxf((float)pk.h2[0] * sc0 + sh0, 0.f);
    const float n1 = fmaxf((float)pk.h2[1] * sc1 + sh1, 0.f);
    pk.h2[0] = (_Float16)n0; pk.h2[1] = (_Float16)n1;
    h[idx] = pk.u;
}

// ---------------------------------------------------------------------------
// norm_feat: GN+affine+ReLU on plain fp32 features, in place.
// ---------------------------------------------------------------------------
__global__ __launch_bounds__(256) void norm_feat(
    float* __restrict__ h, const float* __restrict__ stats,
    const float* __restrict__ gamma, const float* __restrict__ beta,
    int L, float invN)
{
    const int row = blockIdx.y;
    const int b = row >> 9, oc = row & 511;
    const int t = blockIdx.x * 256 + threadIdx.x;
    if (t >= L) return;
    const float mu = stats[2 * b] * invN;
    const float var = stats[2 * b + 1] * invN - mu * mu;
    const float rs = rsqrtf(var + 1e-5f);
    const float sc = rs * gamma[oc];
    const float sh = beta[oc] - mu * sc;
    const size_t i = (size_t)row * L + t;
    const float v = h[i] * sc + sh;
    h[i] = v > 0.f ? v : 0.f;
}

// ---------------------------------------------------------------------------
// aa_kernel: row squared-norms of features.
// ---------------------------------------------------------------------------
__global__ __launch_bounds__(256) void aa_kernel(
    const float* __restrict__ fX, const float* __restrict__ fY,
    float* __restrict__ aaX, float* __restrict__ aaY)
{
    const int wave = threadIdx.x >> 6, lane = threadIdx.x & 63;
    const int R = blockIdx.x * 4 + wave;
    const float* f = (R < 8192) ? fX : fY;
    const int r = R & 8191;
    const float* row = f + (size_t)r * 198;
    float s = 0.f;
#pragma unroll
    for (int k = 0; k < 4; ++k) {
        const int j = lane + 64 * k;
        if (j < 198) { const float v = row[j]; s += v * v; }
    }
#pragma unroll
    for (int off = 32; off > 0; off >>= 1) s += __shfl_xor(s, off);
    if (lane == 0) ((R < 8192) ? aaX : aaY)[r] = s;
}

// ---------------------------------------------------------------------------
// cost_kernel: M = f16( min(50 * max(aa[n]+bb[m]-2<p,q>, 0), 65000) ) == 100*C
// ---------------------------------------------------------------------------
__global__ __launch_bounds__(256) void cost_kernel(
    const float* __restrict__ fX, const float* __restrict__ fY,
    const float* __restrict__ aaX, const float* __restrict__ aaY,
    _Float16* __restrict__ Cxy, _Float16* __restrict__ Cxx,
    _Float16* __restrict__ Cyy, _Float16* __restrict__ CTxy)
{
    const int z = blockIdx.z;
    const int mat = z >> 4, b = z & 15;
    const float *P, *Q, *aP, *aQ;
    _Float16 *Cm, *CT = nullptr;
    if (mat == 0) { P = fX; Q = fY; aP = aaX; aQ = aaY; Cm = Cxy; CT = CTxy; }
    else if (mat == 1) { P = fX; Q = fX; aP = aaX; aQ = aaX; Cm = Cxx; }
    else { P = fY; Q = fY; aP = aaY; aQ = aaY; Cm = Cyy; }

    const int n0 = blockIdx.x * 32, m0 = blockIdx.y * 32;
    __shared__ float LP[32][201], LQ[32][201];
    const int tid = threadIdx.x;
    for (int e = tid; e < 32 * 198; e += 256) {
        const int r = e / 198, d = e % 198;
        LP[r][d] = P[((size_t)b * 512 + n0 + r) * 198 + d];
        LQ[r][d] = Q[((size_t)b * 512 + m0 + r) * 198 + d];
    }
    __syncthreads();

    const int tx = tid & 31, ty = tid >> 5;
    float dot[4] = {0.f, 0.f, 0.f, 0.f};
    for (int d = 0; d < 198; ++d) {
        const float qv = LQ[tx][d];
#pragma unroll
        for (int q = 0; q < 4; ++q) dot[q] += LP[ty + 8 * q][d] * qv;
    }
    const int mm = m0 + tx;
    const float bbm = aQ[b * 512 + mm];
#pragma unroll
    for (int q = 0; q < 4; ++q) {
        const int n = n0 + ty + 8 * q;
        float c = 50.f * fmaxf(aP[b * 512 + n] + bbm - 2.f * dot[q], 0.f);  // == 100*C
        c = fminf(c, 65000.f);
        const _Float16 ch = (_Float16)c;
        Cm[((size_t)b * 512 + n) * 512 + mm] = ch;
        if (CT) CT[((size_t)b * 512 + mm) * 512 + n] = ch;
    }
}

// ---------------------------------------------------------------------------
// sink_update: dst[i] = eps*log512 - eps*LSE_j( 400*src[j] - 4*M100[i,j] )
// grid (32, 48); 4 waves/block, 4 rows/wave; src vector hoisted to registers.
// (round-7 verbatim — proven, full-device parallelism)
// ---------------------------------------------------------------------------
__global__ __launch_bounds__(256) void sink_update(
    float* __restrict__ dst, const float* __restrict__ src,
    const _Float16* __restrict__ M0, const _Float16* __restrict__ M1,
    const _Float16* __restrict__ M2)
{
    const int p = blockIdx.y;
    const int mat = p >> 4, b = p & 15;
    const _Float16* M = (mat == 0) ? M0 : ((mat == 1) ? M1 : M2);
    const float* sp = src + (size_t)p * 512;
    __shared__ float sf[512];
    const int tid = threadIdx.x;
    sf[tid] = sp[tid] * INV_EPS_SINK;
    sf[tid + 256] = sp[tid + 256] * INV_EPS_SINK;
    __syncthreads();

    const int wave = tid >> 6, lane = tid & 63;
    float s8[8];
    {
        const float4 sa = *(const float4*)&sf[lane * 8];
        const float4 sb = *(const float4*)&sf[lane * 8 + 4];
        s8[0]=sa.x; s8[1]=sa.y; s8[2]=sa.z; s8[3]=sa.w;
        s8[4]=sb.x; s8[5]=sb.y; s8[6]=sb.z; s8[7]=sb.w;
    }

#pragma unroll
    for (int rr = 0; rr < 4; ++rr) {
        const int i = blockIdx.x * 16 + wave * 4 + rr;
        const half8v rv = *(const half8v*)(M + ((size_t)b * 512 + i) * 512 + lane * 8);
        float a8[8];
#pragma unroll
        for (int k = 0; k < 8; ++k) a8[k] = fmaf(-4.f, (float)rv[k], s8[k]);
        float mx = a8[0];
#pragma unroll
        for (int k = 1; k < 8; ++k) mx = fmaxf(mx, a8[k]);
        float ss = 0.f;
#pragma unroll
        for (int k = 0; k < 8; ++k) ss += __expf(a8[k] - mx);
#pragma unroll
        for (int off = 32; off > 0; off >>= 1) {
            const float om = __shfl_xor(mx, off);
            const float os = __shfl_xor(ss, off);
            const float nm = fmaxf(mx, om);
            ss = ss * __expf(mx - nm) + os * __expf(om - nm);
            mx = nm;
        }
        if (lane == 0)
            dst[(size_t)p * 512 + i] = EPS_LOG512 - EPS_SINK * (mx + logf(ss));
    }
}

// ---------------------------------------------------------------------------
__global__ __launch_bounds__(256) void final_kernel(
    const float* __restrict__ f, const float* __restrict__ g,
    float* __restrict__ out)
{
    const int b = blockIdx.x, tid = threadIdx.x;
    __shared__ float red[256];
    float a = 0.f;
    for (int n = tid; n < 512; n += 256) {
        const float xy = f[(0 * 16 + b) * 512 + n] + g[(0 * 16 + b) * 512 + n];
        const float xx = f[(1 * 16 + b) * 512 + n] + g[(1 * 16 + b) * 512 + n];
        const float yy = f[(2 * 16 + b) * 512 + n] + g[(2 * 16 + b) * 512 + n];
        a += xy - 0.5f * (xx + yy);
    }
    red[tid] = a;
    __syncthreads();
    for (int s2 = 128; s2 > 0; s2 >>= 1) {
        if (tid < s2) red[tid] += red[tid + s2];
        __syncthreads();
    }
    if (tid == 0) out[b] = red[0] * (1.0f / 512.0f);
}

// ---------------------------------------------------------------------------
extern "C" void kernel_launch(void* const* d_in, const int* in_sizes, int n_in,
                              void* d_out, int out_size, void* d_ws, size_t ws_size,
                              hipStream_t stream)
{
    (void)in_sizes; (void)n_in; (void)out_size; (void)ws_size;
    char* ws = (char*)d_ws;
    const float* yhat = (const float*)d_in[0];
    const float* ysig = (const float*)d_in[1];
    const float* Wl[5]; const float* gl[5]; const float* bl[5];
    for (int i = 0; i < 5; ++i) {
        Wl[i] = (const float*)d_in[2 + 3 * i];
        gl[i] = (const float*)d_in[3 + 3 * i];
        bl[i] = (const float*)d_in[4 + 3 * i];
    }
    float* out = (float*)d_out;
    float* statsA = (float*)(ws + O_STATS);

    _Float16* w1hi = (_Float16*)(ws + O_W1HI); _Float16* w1lo = (_Float16*)(ws + O_W1LO);
    _Float16* w2hi = (_Float16*)(ws + O_W2HI); _Float16* w2lo = (_Float16*)(ws + O_W2LO);
    _Float16* w3hi = (_Float16*)(ws + O_W3HI); _Float16* w3lo = (_Float16*)(ws + O_W3LO);
    _Float16* w4hi = (_Float16*)(ws + O_W4HI); _Float16* w4lo = (_Float16*)(ws + O_W4LO);
    _Float16* h0 = (_Float16*)(ws + O_H0);
    _Float16* h1 = (_Float16*)(ws + O_H1);
    _Float16* h2 = (_Float16*)(ws + O_H2);
    _Float16* h3 = (_Float16*)(ws + O_H3);

    hipMemsetAsync(statsA, 0, 512 * sizeof(float), stream);
    prep_w<<<dim3(1024, 4), 256, 0, stream>>>(Wl[1], Wl[2], Wl[3], Wl[4],
        w1hi, w1lo, w2hi, w2lo, w3hi, w3lo, w4hi, w4lo);

    for (int s = 0; s < 2; ++s) {
        const float* wav = (s == 0) ? yhat : ysig;
        float* st = statsA + (size_t)s * 160;
        float* ft = (float*)(ws + ((s == 0) ? O_FEATX : O_FEATY));

        conv0_store<<<dim3(25, 16), 256, 0, stream>>>(wav, Wl[0], h0, st);
        norm_h0<<<dim3(4, 8192), 256, 0, stream>>>(h0, st, gl[0], bl[0]);

        conv1_mfma<<<dim3(25, 4, 16), 256, 0, stream>>>(
            h0, w1hi, w1lo, h1, st + 32);
        norm_pair<<<dim3(7, 4096), 256, 0, stream>>>(
            (uint*)h1, st + 32, gl[1], bl[1], 1598, 1.f / (512.f * 1598.f));

        conv_mfma<true><<<dim3(13, 4, 16), 256, 0, stream>>>(
            h1, w2hi, w2lo, h2, nullptr, st + 64, 1598, 798);
        norm_pair<<<dim3(4, 4096), 256, 0, stream>>>(
            (uint*)h2, st + 64, gl[2], bl[2], 798, 1.f / (512.f * 798.f));

        conv_mfma<true><<<dim3(7, 4, 16), 256, 0, stream>>>(
            h2, w3hi, w3lo, h3, nullptr, st + 96, 798, 398);
        norm_pair<<<dim3(2, 4096), 256, 0, stream>>>(
            (uint*)h3, st + 96, gl[3], bl[3], 398, 1.f / (512.f * 398.f));

        conv_mfma<false><<<dim3(4, 4, 16), 256, 0, stream>>>(
            h3, w4hi, w4lo, nullptr, ft, st + 128, 398, 198);
        norm_feat<<<dim3(1, 8192), 256, 0, stream>>>(
            ft, st + 128, gl[4], bl[4], 198, 1.f / (512.f * 198.f));
    }

    float* featX = (float*)(ws + O_FEATX);
    float* featY = (float*)(ws + O_FEATY);
    aa_kernel<<<4096, 256, 0, stream>>>(featX, featY, (float*)(ws + O_AAX), (float*)(ws + O_AAY));
    cost_kernel<<<dim3(16, 16, 48), 256, 0, stream>>>(
        featX, featY, (float*)(ws + O_AAX), (float*)(ws + O_AAY),
        (_Float16*)(ws + O_CXY), (_Float16*)(ws + O_CXX), (_Float16*)(ws + O_CYY),
        (_Float16*)(ws + O_CTXY));

    hipMemsetAsync(ws + O_F, 0, 2 * 24576 * sizeof(float), stream);

    for (int it = 0; it < 50; ++it) {
        sink_update<<<dim3(32, 48), 256, 0, stream>>>(
            (float*)(ws + O_G), (float*)(ws + O_F),
            (_Float16*)(ws + O_CTXY), (_Float16*)(ws + O_CXX), (_Float16*)(ws + O_CYY));
        sink_update<<<dim3(32, 48), 256, 0, stream>>>(
            (float*)(ws + O_F), (float*)(ws + O_G),
            (_Float16*)(ws + O_CXY), (_Float16*)(ws + O_CXX), (_Float16*)(ws + O_CYY));
    }

    final_kernel<<<16, 256, 0, stream>>>((float*)(ws + O_F), (float*)(ws + O_G), out);
}

// Round 11
// 2583.051 us; speedup vs baseline: 1.9864x; 1.0541x over previous
//
#include <hip/hip_runtime.h>

typedef unsigned int uint;
typedef unsigned short ushort;
using half8v  = __attribute__((ext_vector_type(8))) _Float16;
using half4v  = __attribute__((ext_vector_type(4))) _Float16;
using float4v = __attribute__((ext_vector_type(4))) float;

#define EPS_SINK 0.0025f
#define INV_EPS_SINK 400.0f
#define EPS_LOG512 0.015595811562598769f

// ---- workspace layout (BYTE offsets), peak ~165 MB ----
static const size_t O_W1HI = 0ull;             // 512*512*8 f16 = 4,194,304 B
static const size_t O_W1LO = 4194304ull;
static const size_t O_W2HI = 8388608ull;
static const size_t O_W2LO = 10485760ull;
static const size_t O_W3HI = 12582912ull;
static const size_t O_W3LO = 14680064ull;
static const size_t O_W4HI = 16777216ull;
static const size_t O_W4LO = 18874368ull;
static const size_t O_H0   = 20971520ull;      // 16*512*6400 f16 = 104,857,600 B
static const size_t O_H1   = 125829120ull;     // 16*256*1598 uint = 26,181,632 B
static const size_t O_H2   = 20971520ull;      // alias h0 (dead after conv1)
static const size_t O_H3   = 34045952ull;
static const size_t O_FEATX= 152010752ull;     // 16*512*198 fp32
static const size_t O_FEATY= 158498816ull;
static const size_t O_STATS= 164986880ull;     // 512 floats
// cost phase (weights/h0/h1 all dead).  C stored f16, value = 100*C:
static const size_t O_CXY  = 0ull;             // 8,388,608 B each
static const size_t O_CTXY = 8388608ull;
static const size_t O_CXX  = 16777216ull;
static const size_t O_CYY  = 25165824ull;
static const size_t O_AAX  = 33554432ull;
static const size_t O_AAY  = 33587200ull;
static const size_t O_F    = 33619968ull;      // 3*16*512 fp32
static const size_t O_G    = 33718272ull;

// ---------------------------------------------------------------------------
// prep_w: split conv weights fp32 -> f16 hi/lo. W1 [oc][ic][8 taps];
// W2-4 pair-interleaved [oc][icpair][dt0 icA, dt0 icB, dt1 icA, ...].
// ---------------------------------------------------------------------------
__global__ __launch_bounds__(256) void prep_w(
    const float* __restrict__ W1, const float* __restrict__ W2,
    const float* __restrict__ W3, const float* __restrict__ W4,
    _Float16* __restrict__ w1hi, _Float16* __restrict__ w1lo,
    _Float16* __restrict__ w2hi, _Float16* __restrict__ w2lo,
    _Float16* __restrict__ w3hi, _Float16* __restrict__ w3lo,
    _Float16* __restrict__ w4hi, _Float16* __restrict__ w4lo)
{
    const int layer = blockIdx.y;
    const int e = blockIdx.x * 256 + threadIdx.x;
    float v[8];
    _Float16 *dh, *dl;
    if (layer == 0) {
        const float4 a = *(const float4*)(W1 + (size_t)e * 8);
        const float4 c = *(const float4*)(W1 + (size_t)e * 8 + 4);
        v[0]=a.x; v[1]=a.y; v[2]=a.z; v[3]=a.w; v[4]=c.x; v[5]=c.y; v[6]=c.z; v[7]=c.w;
        dh = w1hi; dl = w1lo;
    } else {
        if (e >= 131072) return;
        const float* W = (layer == 1) ? W2 : (layer == 2) ? W3 : W4;
        dh = (layer == 1) ? w2hi : (layer == 2) ? w3hi : w4hi;
        dl = (layer == 1) ? w2lo : (layer == 2) ? w3lo : w4lo;
        const int oc = e >> 8, icp = e & 255;
        const float4 a = *(const float4*)(W + ((size_t)oc * 512 + icp * 2) * 4);
        const float4 c = *(const float4*)(W + ((size_t)oc * 512 + icp * 2 + 1) * 4);
        v[0]=a.x; v[1]=c.x; v[2]=a.y; v[3]=c.y; v[4]=a.z; v[5]=c.z; v[6]=a.w; v[7]=c.w;
    }
    half8v hi, lo;
#pragma unroll
    for (int k = 0; k < 8; ++k) {
        const _Float16 h = (_Float16)v[k];
        hi[k] = h;
        lo[k] = (_Float16)(v[k] - (float)h);
    }
    *(half8v*)(dh + (size_t)e * 8) = hi;
    *(half8v*)(dl + (size_t)e * 8) = lo;
}

// ---------------------------------------------------------------------------
// conv0_store: raw conv0 (k=10,s=5) -> h0 f16 [b][512][6400] + GN stats.
// ---------------------------------------------------------------------------
__global__ __launch_bounds__(256) void conv0_store(
    const float* __restrict__ wav, const float* __restrict__ W0,
    _Float16* __restrict__ h0, float* __restrict__ stats)
{
    __shared__ float LW[5120];
    __shared__ float red[2][256];
    const int tid = threadIdx.x;
    for (int e = tid; e < 5120; e += 256) LW[e] = W0[e];

    const int b = blockIdx.y;
    const int t = blockIdx.x * 256 + tid;
    const bool valid = (t < 6399);
    float xv[10];
#pragma unroll
    for (int d = 0; d < 10; ++d) xv[d] = 0.f;
    if (valid) {
        const float* wp = wav + (size_t)b * 32000 + (size_t)t * 5;
#pragma unroll
        for (int d = 0; d < 10; ++d) xv[d] = wp[d];
    }
    __syncthreads();

    float lsum = 0.f, lsq = 0.f;
    _Float16* hb = h0 + (size_t)b * 512 * 6400;
    for (int oc = 0; oc < 512; ++oc) {
        float a = 0.f;
#pragma unroll
        for (int d = 0; d < 10; ++d) a += LW[oc * 10 + d] * xv[d];
        if (valid) {
            hb[(size_t)oc * 6400 + t] = (_Float16)a;
            lsum += a; lsq += a * a;
        }
    }
    red[0][tid] = lsum; red[1][tid] = lsq;
    __syncthreads();
    for (int s2 = 128; s2 > 0; s2 >>= 1) {
        if (tid < s2) { red[0][tid] += red[0][tid + s2]; red[1][tid] += red[1][tid + s2]; }
        __syncthreads();
    }
    if (tid == 0) {
        atomicAdd(&stats[2 * b], red[0][0]);
        atomicAdd(&stats[2 * b + 1], red[1][0]);
    }
}

// ---------------------------------------------------------------------------
// norm_h0: in-place GN0 + affine + ReLU on h0 f16; zeroes tail slot 6399.
// ---------------------------------------------------------------------------
__global__ __launch_bounds__(256) void norm_h0(
    _Float16* __restrict__ h0, const float* __restrict__ stats,
    const float* __restrict__ gamma, const float* __restrict__ beta)
{
    const int row = blockIdx.y;
    const int b = row >> 9, oc = row & 511;
    const int t8 = (blockIdx.x * 256 + threadIdx.x) * 8;
    if (t8 >= 6400) return;
    const float invN = 1.f / (512.f * 6399.f);
    const float mu = stats[2 * b] * invN;
    const float var = stats[2 * b + 1] * invN - mu * mu;
    const float rs = rsqrtf(var + 1e-5f);
    const float sc = rs * gamma[oc];
    const float sh = beta[oc] - mu * sc;
    _Float16* p = h0 + (size_t)row * 6400 + t8;
    half8v v = *(half8v*)p;
#pragma unroll
    for (int k = 0; k < 8; ++k) {
        const float f = (t8 + k < 6399) ? fmaxf((float)v[k] * sc + sh, 0.f) : 0.f;
        v[k] = (_Float16)f;
    }
    *(half8v*)p = v;
}

// ---------------------------------------------------------------------------
// conv1_mfma: layer1 (K=8,S=4) from NORMALIZED h0. 128oc x 128t tile, 4 waves,
// each wave 4x4 MFMA tiles (64 MFMAs/iter). W compensated hi/lo (2 MFMAs).
// Output f16 pair-interleaved [b][256 pairs][1598][2] + GN1 stats.
// ---------------------------------------------------------------------------
__global__ __launch_bounds__(256) void conv1_mfma(
    const _Float16* __restrict__ h0,
    const _Float16* __restrict__ w1hi, const _Float16* __restrict__ w1lo,
    _Float16* __restrict__ oh, float* __restrict__ stats1)
{
    __shared__ _Float16 LWhi[2][128][40], LWlo[2][128][40];
    __shared__ _Float16 LX[8][528];               // 520 staged + pad
    __shared__ float red[2][256];

    const int tid  = threadIdx.x;
    const int lane = tid & 63, wv = tid >> 6;
    const int m    = lane & 15, quad = lane >> 4;
    const int wv2  = wv >> 1, wvt = wv & 1;
    const int b    = blockIdx.z;
    const int ocb  = blockIdx.y * 128;
    const int t0   = blockIdx.x * 128;
    const int Lout = 1598;

    float4v acc[4][4];
#pragma unroll
    for (int i = 0; i < 4; ++i)
#pragma unroll
        for (int j = 0; j < 4; ++j) acc[i][j] = (float4v){0.f, 0.f, 0.f, 0.f};

    const _Float16* hb = h0 + (size_t)b * 512 * 6400;
    const int gbase = t0 * 4;
    const int lim = 6400 - gbase;   // valid f16s in padded row from gbase

    for (int ic0 = 0; ic0 < 512; ic0 += 8) {
        __syncthreads();
        // --- stage W: 1024 frag-units (k32l, oc, q)
#pragma unroll
        for (int r = 0; r < 4; ++r) {
            const int e = tid + r * 256;
            const int k32l = e >> 9, oc = (e >> 2) & 127, q = e & 3;
            const size_t so = ((size_t)(ocb + oc) * 512 + ic0 + k32l * 4 + q) * 8;
            *(half8v*)&LWhi[k32l][oc][q * 8] = *(const half8v*)(w1hi + so);
            *(half8v*)&LWlo[k32l][oc][q * 8] = *(const half8v*)(w1lo + so);
        }
        // --- stage X: pure copy (8 ic x 65 16B-units = 520)
        for (int e = tid; e < 520; e += 256) {
            const int ic = e / 65, u = e - ic * 65;
            const _Float16* src = hb + (size_t)(ic0 + ic) * 6400 + gbase + u * 8;
            half8v val;
            if (u * 8 + 7 < lim) val = *(const half8v*)src;
            else {
#pragma unroll
                for (int k = 0; k < 8; ++k) val[k] = (u * 8 + k < lim) ? src[k] : (_Float16)0.f;
            }
            *(half8v*)&LX[ic][u * 8] = val;
        }
        __syncthreads();
        // --- compute: 2 K-steps of 32, 4x4 tiles/wave
#pragma unroll
        for (int k32l = 0; k32l < 2; ++k32l) {
            half8v ahi[4], alo[4], bf[4];
#pragma unroll
            for (int i = 0; i < 4; ++i) {
                const int ocl = wv2 * 64 + i * 16 + m;
                ahi[i] = *(const half8v*)&LWhi[k32l][ocl][quad * 8];
                alo[i] = *(const half8v*)&LWlo[k32l][ocl][quad * 8];
            }
            const int icl = k32l * 4 + quad;
#pragma unroll
            for (int j = 0; j < 4; ++j) {
                const int tl = wvt * 64 + j * 16 + m;
                const half4v x0 = *(const half4v*)&LX[icl][tl * 4];
                const half4v x1 = *(const half4v*)&LX[icl][tl * 4 + 4];
                bf[j] = __builtin_shufflevector(x0, x1, 0, 1, 2, 3, 4, 5, 6, 7);
            }
#pragma unroll
            for (int i = 0; i < 4; ++i)
#pragma unroll
                for (int j = 0; j < 4; ++j) {
                    acc[i][j] = __builtin_amdgcn_mfma_f32_16x16x32_f16(ahi[i], bf[j], acc[i][j], 0, 0, 0);
                    acc[i][j] = __builtin_amdgcn_mfma_f32_16x16x32_f16(alo[i], bf[j], acc[i][j], 0, 0, 0);
                }
        }
    }

    // --- epilogue: pack f16 pairs + stats
    float lsum = 0.f, lsq = 0.f;
    uint* ohU = (uint*)oh;
#pragma unroll
    for (int i = 0; i < 4; ++i) {
        const int ocb2 = ocb + wv2 * 64 + i * 16 + quad * 4;
#pragma unroll
        for (int j = 0; j < 4; ++j) {
            const int t = t0 + wvt * 64 + j * 16 + m;
            if (t < Lout) {
#pragma unroll
                for (int pr = 0; pr < 2; ++pr) {
                    const float v0 = acc[i][j][pr * 2], v1 = acc[i][j][pr * 2 + 1];
                    union { uint u; _Float16 h[2]; } pk;
                    pk.h[0] = (_Float16)v0; pk.h[1] = (_Float16)v1;
                    const uint p = (uint)((ocb2 >> 1) + pr);
                    ohU[((size_t)(b * 256 + p)) * Lout + t] = pk.u;
                    lsum += v0 + v1; lsq += v0 * v0 + v1 * v1;
                }
            }
        }
    }
    __syncthreads();
    red[0][tid] = lsum; red[1][tid] = lsq;
    __syncthreads();
    for (int s2 = 128; s2 > 0; s2 >>= 1) {
        if (tid < s2) { red[0][tid] += red[0][tid + s2]; red[1][tid] += red[1][tid + s2]; }
        __syncthreads();
    }
    if (tid == 0) {
        atomicAdd(&stats1[2 * b], red[0][0]);
        atomicAdd(&stats1[2 * b + 1], red[1][0]);
    }
}

// ---------------------------------------------------------------------------
// conv_mfma: layers 2-4 (K=4,S=2). 128oc x 64t tile. Input pair-interleaved
// f16. PAIRED: f16 pair-interleaved out; else fp32 plain.  (round-9 verbatim)
// ---------------------------------------------------------------------------
template <bool PAIRED>
__global__ __launch_bounds__(256) void conv_mfma(
    const _Float16* __restrict__ x,
    const _Float16* __restrict__ whi, const _Float16* __restrict__ wlo,
    _Float16* __restrict__ oh, float* __restrict__ oplain,
    float* __restrict__ stats, int Lin, int Lout)
{
    __shared__ _Float16 LWhi[2][128][40], LWlo[2][128][40];
    __shared__ _Float16 LX[8][272];
    __shared__ float red[2][256];

    const int tid  = threadIdx.x;
    const int lane = tid & 63, wv = tid >> 6;
    const int m    = lane & 15, quad = lane >> 4;
    const int wv2  = wv >> 1, wvt = wv & 1;
    const int b    = blockIdx.z;
    const int ocb  = blockIdx.y * 128;
    const int t0   = blockIdx.x * 64;

    float4v acc[4][2];
#pragma unroll
    for (int i = 0; i < 4; ++i)
#pragma unroll
        for (int j = 0; j < 2; ++j) acc[i][j] = (float4v){0.f, 0.f, 0.f, 0.f};

    const int lim = (Lin - t0 * 2) * 2;

    for (int ic0 = 0; ic0 < 512; ic0 += 16) {
        __syncthreads();
        // --- stage W: 1024 frag-units
#pragma unroll
        for (int r = 0; r < 4; ++r) {
            const int e = tid + r * 256;
            const int k32l = e >> 9, oc = (e >> 2) & 127, q = e & 3;
            const size_t so = ((size_t)(ocb + oc) * 256 + (ic0 >> 1) + k32l * 4 + q) * 8;
            *(half8v*)&LWhi[k32l][oc][q * 8] = *(const half8v*)(whi + so);
            *(half8v*)&LWlo[k32l][oc][q * 8] = *(const half8v*)(wlo + so);
        }
        // --- stage X (copy, 272 16B-units)
        for (int e = tid; e < 272; e += 256) {
            const int pl = e / 34, u = e - pl * 34;
            const _Float16* src = x + ((size_t)(b * 256 + (ic0 >> 1) + pl)) * ((size_t)Lin * 2)
                                   + (size_t)t0 * 4 + (size_t)u * 8;
            half8v val;
            if (u * 8 + 7 < lim) val = *(const half8v*)src;
            else {
#pragma unroll
                for (int k = 0; k < 8; ++k) val[k] = (u * 8 + k < lim) ? src[k] : (_Float16)0.f;
            }
            *(half8v*)&LX[pl][u * 8] = val;
        }
        __syncthreads();
        // --- compute
#pragma unroll
        for (int k32l = 0; k32l < 2; ++k32l) {
            half8v ahi[4], alo[4], bf[2];
#pragma unroll
            for (int i = 0; i < 4; ++i) {
                const int ocl = wv2 * 64 + i * 16 + m;
                ahi[i] = *(const half8v*)&LWhi[k32l][ocl][quad * 8];
                alo[i] = *(const half8v*)&LWlo[k32l][ocl][quad * 8];
            }
#pragma unroll
            for (int j = 0; j < 2; ++j) {
                const int tl = wvt * 32 + j * 16 + m;
                const int pl = k32l * 4 + quad;
                const half4v x0 = *(const half4v*)&LX[pl][tl * 4];
                const half4v x1 = *(const half4v*)&LX[pl][tl * 4 + 4];
                bf[j] = __builtin_shufflevector(x0, x1, 0, 1, 2, 3, 4, 5, 6, 7);
            }
#pragma unroll
            for (int i = 0; i < 4; ++i)
#pragma unroll
                for (int j = 0; j < 2; ++j) {
                    acc[i][j] = __builtin_amdgcn_mfma_f32_16x16x32_f16(ahi[i], bf[j], acc[i][j], 0, 0, 0);
                    acc[i][j] = __builtin_amdgcn_mfma_f32_16x16x32_f16(alo[i], bf[j], acc[i][j], 0, 0, 0);
                }
        }
    }

    // --- epilogue
    float lsum = 0.f, lsq = 0.f;
    uint* ohU = (uint*)oh;
#pragma unroll
    for (int i = 0; i < 4; ++i) {
        const int ocb2 = ocb + wv2 * 64 + i * 16 + quad * 4;
#pragma unroll
        for (int j = 0; j < 2; ++j) {
            const int t = t0 + wvt * 32 + j * 16 + m;
            if (t < Lout) {
                if (PAIRED) {
#pragma unroll
                    for (int pr = 0; pr < 2; ++pr) {
                        const float v0 = acc[i][j][pr * 2], v1 = acc[i][j][pr * 2 + 1];
                        union { uint u; _Float16 h[2]; } pk;
                        pk.h[0] = (_Float16)v0; pk.h[1] = (_Float16)v1;
                        const uint p = (uint)((ocb2 >> 1) + pr);
                        ohU[((size_t)(b * 256 + p)) * Lout + t] = pk.u;
                        lsum += v0 + v1; lsq += v0 * v0 + v1 * v1;
                    }
                } else {
#pragma unroll
                    for (int r = 0; r < 4; ++r) {
                        const float v = acc[i][j][r];
                        oplain[((size_t)(b * 512 + ocb2 + r)) * Lout + t] = v;
                        lsum += v; lsq += v * v;
                    }
                }
            }
        }
    }
    __syncthreads();
    red[0][tid] = lsum; red[1][tid] = lsq;
    __syncthreads();
    for (int s2 = 128; s2 > 0; s2 >>= 1) {
        if (tid < s2) { red[0][tid] += red[0][tid + s2]; red[1][tid] += red[1][tid + s2]; }
        __syncthreads();
    }
    if (tid == 0) {
        atomicAdd(&stats[2 * b], red[0][0]);
        atomicAdd(&stats[2 * b + 1], red[1][0]);
    }
}

// ---------------------------------------------------------------------------
// norm_pair: GN(1grp)+affine+ReLU in place on pair-interleaved f16.
// ---------------------------------------------------------------------------
__global__ __launch_bounds__(256) void norm_pair(
    uint* __restrict__ h, const float* __restrict__ stats,
    const float* __restrict__ gamma, const float* __restrict__ beta,
    int L, float invN)
{
    const int row = blockIdx.y;
    const int b = row >> 8, p = row & 255;
    const int t = blockIdx.x * 256 + threadIdx.x;
    if (t >= L) return;
    const int c0 = 2 * p, c1 = 2 * p + 1;
    const float mu = stats[2 * b] * invN;
    const float var = stats[2 * b + 1] * invN - mu * mu;
    const float rs = rsqrtf(var + 1e-5f);
    const float sc0 = rs * gamma[c0], sh0 = beta[c0] - mu * sc0;
    const float sc1 = rs * gamma[c1], sh1 = beta[c1] - mu * sc1;
    const size_t idx = (size_t)row * L + t;
    union { uint u; _Float16 h2[2]; } pk;
    pk.u = h[idx];
    const float n0 = fmaxf((float)pk.h2[0] * sc0 + sh0, 0.f);
    const float n1 = fmaxf((float)pk.h2[1] * sc1 + sh1, 0.f);
    pk.h2[0] = (_Float16)n0; pk.h2[1] = (_Float16)n1;
    h[idx] = pk.u;
}

// ---------------------------------------------------------------------------
// norm_feat: GN+affine+ReLU on plain fp32 features, in place.
// ---------------------------------------------------------------------------
__global__ __launch_bounds__(256) void norm_feat(
    float* __restrict__ h, const float* __restrict__ stats,
    const float* __restrict__ gamma, const float* __restrict__ beta,
    int L, float invN)
{
    const int row = blockIdx.y;
    const int b = row >> 9, oc = row & 511;
    const int t = blockIdx.x * 256 + threadIdx.x;
    if (t >= L) return;
    const float mu = stats[2 * b] * invN;
    const float var = stats[2 * b + 1] * invN - mu * mu;
    const float rs = rsqrtf(var + 1e-5f);
    const float sc = rs * gamma[oc];
    const float sh = beta[oc] - mu * sc;
    const size_t i = (size_t)row * L + t;
    const float v = h[i] * sc + sh;
    h[i] = v > 0.f ? v : 0.f;
}

// ---------------------------------------------------------------------------
// aa_kernel: row squared-norms of features.
// ---------------------------------------------------------------------------
__global__ __launch_bounds__(256) void aa_kernel(
    const float* __restrict__ fX, const float* __restrict__ fY,
    float* __restrict__ aaX, float* __restrict__ aaY)
{
    const int wave = threadIdx.x >> 6, lane = threadIdx.x & 63;
    const int R = blockIdx.x * 4 + wave;
    const float* f = (R < 8192) ? fX : fY;
    const int r = R & 8191;
    const float* row = f + (size_t)r * 198;
    float s = 0.f;
#pragma unroll
    for (int k = 0; k < 4; ++k) {
        const int j = lane + 64 * k;
        if (j < 198) { const float v = row[j]; s += v * v; }
    }
#pragma unroll
    for (int off = 32; off > 0; off >>= 1) s += __shfl_xor(s, off);
    if (lane == 0) ((R < 8192) ? aaX : aaY)[r] = s;
}

// ---------------------------------------------------------------------------
// cost_kernel: M = f16( min(50 * max(aa[n]+bb[m]-2<p,q>, 0), 65000) ) == 100*C
// ---------------------------------------------------------------------------
__global__ __launch_bounds__(256) void cost_kernel(
    const float* __restrict__ fX, const float* __restrict__ fY,
    const float* __restrict__ aaX, const float* __restrict__ aaY,
    _Float16* __restrict__ Cxy, _Float16* __restrict__ Cxx,
    _Float16* __restrict__ Cyy, _Float16* __restrict__ CTxy)
{
    const int z = blockIdx.z;
    const int mat = z >> 4, b = z & 15;
    const float *P, *Q, *aP, *aQ;
    _Float16 *Cm, *CT = nullptr;
    if (mat == 0) { P = fX; Q = fY; aP = aaX; aQ = aaY; Cm = Cxy; CT = CTxy; }
    else if (mat == 1) { P = fX; Q = fX; aP = aaX; aQ = aaX; Cm = Cxx; }
    else { P = fY; Q = fY; aP = aaY; aQ = aaY; Cm = Cyy; }

    const int n0 = blockIdx.x * 32, m0 = blockIdx.y * 32;
    __shared__ float LP[32][201], LQ[32][201];
    const int tid = threadIdx.x;
    for (int e = tid; e < 32 * 198; e += 256) {
        const int r = e / 198, d = e % 198;
        LP[r][d] = P[((size_t)b * 512 + n0 + r) * 198 + d];
        LQ[r][d] = Q[((size_t)b * 512 + m0 + r) * 198 + d];
    }
    __syncthreads();

    const int tx = tid & 31, ty = tid >> 5;
    float dot[4] = {0.f, 0.f, 0.f, 0.f};
    for (int d = 0; d < 198; ++d) {
        const float qv = LQ[tx][d];
#pragma unroll
        for (int q = 0; q < 4; ++q) dot[q] += LP[ty + 8 * q][d] * qv;
    }
    const int mm = m0 + tx;
    const float bbm = aQ[b * 512 + mm];
#pragma unroll
    for (int q = 0; q < 4; ++q) {
        const int n = n0 + ty + 8 * q;
        float c = 50.f * fmaxf(aP[b * 512 + n] + bbm - 2.f * dot[q], 0.f);  // == 100*C
        c = fminf(c, 65000.f);
        const _Float16 ch = (_Float16)c;
        Cm[((size_t)b * 512 + n) * 512 + mm] = ch;
        if (CT) CT[((size_t)b * 512 + mm) * 512 + n] = ch;
    }
}

// ---------------------------------------------------------------------------
// Per-row half-update (round-7 proven math).
// dst[p*512+i] = eps*log512 - eps*LSE_j( 400*src[j] - 4*M100[i,j] )
// ---------------------------------------------------------------------------
static __device__ __forceinline__ void sink_rows(
    float* __restrict__ dst, const float* __restrict__ src,
    const _Float16* __restrict__ Mb, int p, int i0, int lane)
{
    const float* sp = src + (size_t)p * 512;
    float s8[8];
    {
        const float4 sa = *(const float4*)&sp[lane * 8];
        const float4 sb = *(const float4*)&sp[lane * 8 + 4];
        s8[0]=sa.x*400.f; s8[1]=sa.y*400.f; s8[2]=sa.z*400.f; s8[3]=sa.w*400.f;
        s8[4]=sb.x*400.f; s8[5]=sb.y*400.f; s8[6]=sb.z*400.f; s8[7]=sb.w*400.f;
    }
#pragma unroll
    for (int rr = 0; rr < 4; ++rr) {
        const int i = i0 + rr;
        const half8v rv = *(const half8v*)(Mb + (size_t)i * 512 + lane * 8);
        float a8[8];
#pragma unroll
        for (int k = 0; k < 8; ++k) a8[k] = fmaf(-4.f, (float)rv[k], s8[k]);
        float mx = a8[0];
#pragma unroll
        for (int k = 1; k < 8; ++k) mx = fmaxf(mx, a8[k]);
        float ss = 0.f;
#pragma unroll
        for (int k = 0; k < 8; ++k) ss += __expf(a8[k] - mx);
#pragma unroll
        for (int off = 32; off > 0; off >>= 1) {
            const float om = __shfl_xor(mx, off);
            const float os = __shfl_xor(ss, off);
            const float nm = fmaxf(mx, om);
            ss = ss * __expf(mx - nm) + os * __expf(om - nm);
            mx = nm;
        }
        if (lane == 0)
            dst[(size_t)p * 512 + i] = EPS_LOG512 - EPS_SINK * (mx + logf(ss));
    }
}

// ---------------------------------------------------------------------------
// sink_update: one half-update per launch; grid (32,48), 256 thr.
// ---------------------------------------------------------------------------
__global__ __launch_bounds__(256) void sink_update(
    float* __restrict__ dst, const float* __restrict__ src,
    const _Float16* __restrict__ M0, const _Float16* __restrict__ M1,
    const _Float16* __restrict__ M2)
{
    const int p = blockIdx.y;
    const int mat = p >> 4, b = p & 15;
    const _Float16* M = ((mat == 0) ? M0 : ((mat == 1) ? M1 : M2)) + (size_t)b * 512 * 512;
    const int wave = threadIdx.x >> 6, lane = threadIdx.x & 63;
    const int i0 = blockIdx.x * 16 + wave * 4;
    sink_rows(dst, src, M, p, i0, lane);
}

// ---------------------------------------------------------------------------
__global__ __launch_bounds__(256) void final_kernel(
    const float* __restrict__ f, const float* __restrict__ g,
    float* __restrict__ out)
{
    const int b = blockIdx.x, tid = threadIdx.x;
    __shared__ float red[256];
    float a = 0.f;
    for (int n = tid; n < 512; n += 256) {
        const float xy = f[(0 * 16 + b) * 512 + n] + g[(0 * 16 + b) * 512 + n];
        const float xx = f[(1 * 16 + b) * 512 + n] + g[(1 * 16 + b) * 512 + n];
        const float yy = f[(2 * 16 + b) * 512 + n] + g[(2 * 16 + b) * 512 + n];
        a += xy - 0.5f * (xx + yy);
    }
    red[tid] = a;
    __syncthreads();
    for (int s2 = 128; s2 > 0; s2 >>= 1) {
        if (tid < s2) red[tid] += red[tid + s2];
        __syncthreads();
    }
    if (tid == 0) out[b] = red[0] * (1.0f / 512.0f);
}

// ---------------------------------------------------------------------------
extern "C" void kernel_launch(void* const* d_in, const int* in_sizes, int n_in,
                              void* d_out, int out_size, void* d_ws, size_t ws_size,
                              hipStream_t stream)
{
    (void)in_sizes; (void)n_in; (void)out_size; (void)ws_size;
    char* ws = (char*)d_ws;
    const float* yhat = (const float*)d_in[0];
    const float* ysig = (const float*)d_in[1];
    const float* Wl[5]; const float* gl[5]; const float* bl[5];
    for (int i = 0; i < 5; ++i) {
        Wl[i] = (const float*)d_in[2 + 3 * i];
        gl[i] = (const float*)d_in[3 + 3 * i];
        bl[i] = (const float*)d_in[4 + 3 * i];
    }
    float* out = (float*)d_out;
    float* statsA = (float*)(ws + O_STATS);

    _Float16* w1hi = (_Float16*)(ws + O_W1HI); _Float16* w1lo = (_Float16*)(ws + O_W1LO);
    _Float16* w2hi = (_Float16*)(ws + O_W2HI); _Float16* w2lo = (_Float16*)(ws + O_W2LO);
    _Float16* w3hi = (_Float16*)(ws + O_W3HI); _Float16* w3lo = (_Float16*)(ws + O_W3LO);
    _Float16* w4hi = (_Float16*)(ws + O_W4HI); _Float16* w4lo = (_Float16*)(ws + O_W4LO);
    _Float16* h0 = (_Float16*)(ws + O_H0);
    _Float16* h1 = (_Float16*)(ws + O_H1);
    _Float16* h2 = (_Float16*)(ws + O_H2);
    _Float16* h3 = (_Float16*)(ws + O_H3);

    hipMemsetAsync(statsA, 0, 512 * sizeof(float), stream);
    prep_w<<<dim3(1024, 4), 256, 0, stream>>>(Wl[1], Wl[2], Wl[3], Wl[4],
        w1hi, w1lo, w2hi, w2lo, w3hi, w3lo, w4hi, w4lo);

    for (int s = 0; s < 2; ++s) {
        const float* wav = (s == 0) ? yhat : ysig;
        float* st = statsA + (size_t)s * 160;
        float* ft = (float*)(ws + ((s == 0) ? O_FEATX : O_FEATY));

        conv0_store<<<dim3(25, 16), 256, 0, stream>>>(wav, Wl[0], h0, st);
        norm_h0<<<dim3(4, 8192), 256, 0, stream>>>(h0, st, gl[0], bl[0]);

        conv1_mfma<<<dim3(13, 4, 16), 256, 0, stream>>>(
            h0, w1hi, w1lo, h1, st + 32);
        norm_pair<<<dim3(7, 4096), 256, 0, stream>>>(
            (uint*)h1, st + 32, gl[1], bl[1], 1598, 1.f / (512.f * 1598.f));

        conv_mfma<true><<<dim3(13, 4, 16), 256, 0, stream>>>(
            h1, w2hi, w2lo, h2, nullptr, st + 64, 1598, 798);
        norm_pair<<<dim3(4, 4096), 256, 0, stream>>>(
            (uint*)h2, st + 64, gl[2], bl[2], 798, 1.f / (512.f * 798.f));

        conv_mfma<true><<<dim3(7, 4, 16), 256, 0, stream>>>(
            h2, w3hi, w3lo, h3, nullptr, st + 96, 798, 398);
        norm_pair<<<dim3(2, 4096), 256, 0, stream>>>(
            (uint*)h3, st + 96, gl[3], bl[3], 398, 1.f / (512.f * 398.f));

        conv_mfma<false><<<dim3(4, 4, 16), 256, 0, stream>>>(
            h3, w4hi, w4lo, nullptr, ft, st + 128, 398, 198);
        norm_feat<<<dim3(1, 8192), 256, 0, stream>>>(
            ft, st + 128, gl[4], bl[4], 198, 1.f / (512.f * 198.f));
    }

    float* featX = (float*)(ws + O_FEATX);
    float* featY = (float*)(ws + O_FEATY);
    aa_kernel<<<4096, 256, 0, stream>>>(featX, featY, (float*)(ws + O_AAX), (float*)(ws + O_AAY));
    cost_kernel<<<dim3(16, 16, 48), 256, 0, stream>>>(
        featX, featY, (float*)(ws + O_AAX), (float*)(ws + O_AAY),
        (_Float16*)(ws + O_CXY), (_Float16*)(ws + O_CXX), (_Float16*)(ws + O_CYY),
        (_Float16*)(ws + O_CTXY));

    hipMemsetAsync(ws + O_F, 0, 2 * 24576 * sizeof(float), stream);

    float* fptr = (float*)(ws + O_F);
    float* gptr = (float*)(ws + O_G);
    _Float16* cxy  = (_Float16*)(ws + O_CXY);
    _Float16* ctxy = (_Float16*)(ws + O_CTXY);
    _Float16* cxx  = (_Float16*)(ws + O_CXX);
    _Float16* cyy  = (_Float16*)(ws + O_CYY);

    for (int it = 0; it < 50; ++it) {
        sink_update<<<dim3(32, 48), 256, 0, stream>>>(gptr, fptr, ctxy, cxx, cyy);
        sink_update<<<dim3(32, 48), 256, 0, stream>>>(fptr, gptr, cxy, cxx, cyy);
    }

    final_kernel<<<16, 256, 0, stream>>>(fptr, gptr, out);
}

// Round 12
// 2170.133 us; speedup vs baseline: 2.3643x; 1.1903x over previous
//
#include <hip/hip_runtime.h>

typedef unsigned int uint;
typedef unsigned short ushort;
using half8v  = __attribute__((ext_vector_type(8))) _Float16;
using half4v  = __attribute__((ext_vector_type(4))) _Float16;
using float4v = __attribute__((ext_vector_type(4))) float;

#define EPS_SINK 0.0025f
#define INV_EPS_SINK 400.0f
#define EPS_LOG512 0.015595811562598769f

// ---- workspace layout (BYTE offsets), peak ~165 MB ----
static const size_t O_W1   = 0ull;             // 512*512*8 f16 = 4,194,304 B
static const size_t O_W2   = 4194304ull;       // 2,097,152 B each
static const size_t O_W3   = 6291456ull;
static const size_t O_W4   = 8388608ull;
static const size_t O_H0   = 20971520ull;      // 16*512*6400 f16 = 104,857,600 B
static const size_t O_H1   = 125829120ull;     // 16*256*1598 uint = 26,181,632 B
static const size_t O_H2   = 20971520ull;      // alias h0 (dead after conv1)
static const size_t O_H3   = 34045952ull;
static const size_t O_FEATX= 152010752ull;     // 16*512*198 fp32
static const size_t O_FEATY= 158498816ull;
static const size_t O_STATS= 164986880ull;     // 512 floats
// cost phase (weights/h0/h1 all dead).  C stored f16, value = 100*C:
static const size_t O_CXY  = 0ull;             // 8,388,608 B each
static const size_t O_CTXY = 8388608ull;
static const size_t O_CXX  = 16777216ull;
static const size_t O_CYY  = 25165824ull;
static const size_t O_AAX  = 33554432ull;
static const size_t O_AAY  = 33587200ull;
static const size_t O_F    = 33619968ull;      // 3*16*512 fp32
static const size_t O_G    = 33718272ull;

// ---------------------------------------------------------------------------
// prep_w: convert conv weights fp32 -> single f16. W1 [oc][ic][8 taps];
// W2-4 pair-interleaved [oc][icpair][dt0 icA, dt0 icB, dt1 icA, ...].
// ---------------------------------------------------------------------------
__global__ __launch_bounds__(256) void prep_w(
    const float* __restrict__ W1, const float* __restrict__ W2,
    const float* __restrict__ W3, const float* __restrict__ W4,
    _Float16* __restrict__ w1, _Float16* __restrict__ w2,
    _Float16* __restrict__ w3, _Float16* __restrict__ w4)
{
    const int layer = blockIdx.y;
    const int e = blockIdx.x * 256 + threadIdx.x;
    float v[8];
    _Float16* dh;
    if (layer == 0) {
        const float4 a = *(const float4*)(W1 + (size_t)e * 8);
        const float4 c = *(const float4*)(W1 + (size_t)e * 8 + 4);
        v[0]=a.x; v[1]=a.y; v[2]=a.z; v[3]=a.w; v[4]=c.x; v[5]=c.y; v[6]=c.z; v[7]=c.w;
        dh = w1;
    } else {
        if (e >= 131072) return;
        const float* W = (layer == 1) ? W2 : (layer == 2) ? W3 : W4;
        dh = (layer == 1) ? w2 : (layer == 2) ? w3 : w4;
        const int oc = e >> 8, icp = e & 255;
        const float4 a = *(const float4*)(W + ((size_t)oc * 512 + icp * 2) * 4);
        const float4 c = *(const float4*)(W + ((size_t)oc * 512 + icp * 2 + 1) * 4);
        v[0]=a.x; v[1]=c.x; v[2]=a.y; v[3]=c.y; v[4]=a.z; v[5]=c.z; v[6]=a.w; v[7]=c.w;
    }
    half8v hi;
#pragma unroll
    for (int k = 0; k < 8; ++k) hi[k] = (_Float16)v[k];
    *(half8v*)(dh + (size_t)e * 8) = hi;
}

// ---------------------------------------------------------------------------
// conv0_store: raw conv0 (k=10,s=5) -> h0 f16 [b][512][6400] + GN stats.
// ---------------------------------------------------------------------------
__global__ __launch_bounds__(256) void conv0_store(
    const float* __restrict__ wav, const float* __restrict__ W0,
    _Float16* __restrict__ h0, float* __restrict__ stats)
{
    __shared__ float LW[5120];
    __shared__ float red[2][256];
    const int tid = threadIdx.x;
    for (int e = tid; e < 5120; e += 256) LW[e] = W0[e];

    const int b = blockIdx.y;
    const int t = blockIdx.x * 256 + tid;
    const bool valid = (t < 6399);
    float xv[10];
#pragma unroll
    for (int d = 0; d < 10; ++d) xv[d] = 0.f;
    if (valid) {
        const float* wp = wav + (size_t)b * 32000 + (size_t)t * 5;
#pragma unroll
        for (int d = 0; d < 10; ++d) xv[d] = wp[d];
    }
    __syncthreads();

    float lsum = 0.f, lsq = 0.f;
    _Float16* hb = h0 + (size_t)b * 512 * 6400;
    for (int oc = 0; oc < 512; ++oc) {
        float a = 0.f;
#pragma unroll
        for (int d = 0; d < 10; ++d) a += LW[oc * 10 + d] * xv[d];
        if (valid) {
            hb[(size_t)oc * 6400 + t] = (_Float16)a;
            lsum += a; lsq += a * a;
        }
    }
    red[0][tid] = lsum; red[1][tid] = lsq;
    __syncthreads();
    for (int s2 = 128; s2 > 0; s2 >>= 1) {
        if (tid < s2) { red[0][tid] += red[0][tid + s2]; red[1][tid] += red[1][tid + s2]; }
        __syncthreads();
    }
    if (tid == 0) {
        atomicAdd(&stats[2 * b], red[0][0]);
        atomicAdd(&stats[2 * b + 1], red[1][0]);
    }
}

// ---------------------------------------------------------------------------
// norm_h0: in-place GN0 + affine + ReLU on h0 f16; zeroes tail slot 6399.
// ---------------------------------------------------------------------------
__global__ __launch_bounds__(256) void norm_h0(
    _Float16* __restrict__ h0, const float* __restrict__ stats,
    const float* __restrict__ gamma, const float* __restrict__ beta)
{
    const int row = blockIdx.y;
    const int b = row >> 9, oc = row & 511;
    const int t8 = (blockIdx.x * 256 + threadIdx.x) * 8;
    if (t8 >= 6400) return;
    const float invN = 1.f / (512.f * 6399.f);
    const float mu = stats[2 * b] * invN;
    const float var = stats[2 * b + 1] * invN - mu * mu;
    const float rs = rsqrtf(var + 1e-5f);
    const float sc = rs * gamma[oc];
    const float sh = beta[oc] - mu * sc;
    _Float16* p = h0 + (size_t)row * 6400 + t8;
    half8v v = *(half8v*)p;
#pragma unroll
    for (int k = 0; k < 8; ++k) {
        const float f = (t8 + k < 6399) ? fmaxf((float)v[k] * sc + sh, 0.f) : 0.f;
        v[k] = (_Float16)f;
    }
    *(half8v*)p = v;
}

// ---------------------------------------------------------------------------
// conv1_mfma: layer1 (K=8,S=4) from NORMALIZED h0. 128oc x 128t tile, 4 waves,
// each wave 4x4 MFMA tiles (32 MFMAs/iter, single-f16 W). Output f16
// pair-interleaved [b][256 pairs][1598][2] + GN1 stats.
// LDS ~31 KB -> 5 blocks/CU.
// ---------------------------------------------------------------------------
__global__ __launch_bounds__(256) void conv1_mfma(
    const _Float16* __restrict__ h0,
    const _Float16* __restrict__ w1,
    _Float16* __restrict__ oh, float* __restrict__ stats1)
{
    __shared__ _Float16 LW[2][128][40];
    __shared__ _Float16 LX[8][528];               // 520 staged + pad
    __shared__ float red[2][256];

    const int tid  = threadIdx.x;
    const int lane = tid & 63, wv = tid >> 6;
    const int m    = lane & 15, quad = lane >> 4;
    const int wv2  = wv >> 1, wvt = wv & 1;
    const int b    = blockIdx.z;
    const int ocb  = blockIdx.y * 128;
    const int t0   = blockIdx.x * 128;
    const int Lout = 1598;

    float4v acc[4][4];
#pragma unroll
    for (int i = 0; i < 4; ++i)
#pragma unroll
        for (int j = 0; j < 4; ++j) acc[i][j] = (float4v){0.f, 0.f, 0.f, 0.f};

    const _Float16* hb = h0 + (size_t)b * 512 * 6400;
    const int gbase = t0 * 4;
    const int lim = 6400 - gbase;   // valid f16s in padded row from gbase

    for (int ic0 = 0; ic0 < 512; ic0 += 8) {
        __syncthreads();
        // --- stage W: 1024 frag-units (k32l, oc, q)
#pragma unroll
        for (int r = 0; r < 4; ++r) {
            const int e = tid + r * 256;
            const int k32l = e >> 9, oc = (e >> 2) & 127, q = e & 3;
            const size_t so = ((size_t)(ocb + oc) * 512 + ic0 + k32l * 4 + q) * 8;
            *(half8v*)&LW[k32l][oc][q * 8] = *(const half8v*)(w1 + so);
        }
        // --- stage X: pure copy (8 ic x 65 16B-units = 520)
        for (int e = tid; e < 520; e += 256) {
            const int ic = e / 65, u = e - ic * 65;
            const _Float16* src = hb + (size_t)(ic0 + ic) * 6400 + gbase + u * 8;
            half8v val;
            if (u * 8 + 7 < lim) val = *(const half8v*)src;
            else {
#pragma unroll
                for (int k = 0; k < 8; ++k) val[k] = (u * 8 + k < lim) ? src[k] : (_Float16)0.f;
            }
            *(half8v*)&LX[ic][u * 8] = val;
        }
        __syncthreads();
        // --- compute: 2 K-steps of 32, 4x4 tiles/wave
#pragma unroll
        for (int k32l = 0; k32l < 2; ++k32l) {
            half8v a4[4], bf[4];
#pragma unroll
            for (int i = 0; i < 4; ++i) {
                const int ocl = wv2 * 64 + i * 16 + m;
                a4[i] = *(const half8v*)&LW[k32l][ocl][quad * 8];
            }
            const int icl = k32l * 4 + quad;
#pragma unroll
            for (int j = 0; j < 4; ++j) {
                const int tl = wvt * 64 + j * 16 + m;
                const half4v x0 = *(const half4v*)&LX[icl][tl * 4];
                const half4v x1 = *(const half4v*)&LX[icl][tl * 4 + 4];
                bf[j] = __builtin_shufflevector(x0, x1, 0, 1, 2, 3, 4, 5, 6, 7);
            }
#pragma unroll
            for (int i = 0; i < 4; ++i)
#pragma unroll
                for (int j = 0; j < 4; ++j)
                    acc[i][j] = __builtin_amdgcn_mfma_f32_16x16x32_f16(a4[i], bf[j], acc[i][j], 0, 0, 0);
        }
    }

    // --- epilogue: pack f16 pairs + stats
    float lsum = 0.f, lsq = 0.f;
    uint* ohU = (uint*)oh;
#pragma unroll
    for (int i = 0; i < 4; ++i) {
        const int ocb2 = ocb + wv2 * 64 + i * 16 + quad * 4;
#pragma unroll
        for (int j = 0; j < 4; ++j) {
            const int t = t0 + wvt * 64 + j * 16 + m;
            if (t < Lout) {
#pragma unroll
                for (int pr = 0; pr < 2; ++pr) {
                    const float v0 = acc[i][j][pr * 2], v1 = acc[i][j][pr * 2 + 1];
                    union { uint u; _Float16 h[2]; } pk;
                    pk.h[0] = (_Float16)v0; pk.h[1] = (_Float16)v1;
                    const uint p = (uint)((ocb2 >> 1) + pr);
                    ohU[((size_t)(b * 256 + p)) * Lout + t] = pk.u;
                    lsum += v0 + v1; lsq += v0 * v0 + v1 * v1;
                }
            }
        }
    }
    __syncthreads();
    red[0][tid] = lsum; red[1][tid] = lsq;
    __syncthreads();
    for (int s2 = 128; s2 > 0; s2 >>= 1) {
        if (tid < s2) { red[0][tid] += red[0][tid + s2]; red[1][tid] += red[1][tid + s2]; }
        __syncthreads();
    }
    if (tid == 0) {
        atomicAdd(&stats1[2 * b], red[0][0]);
        atomicAdd(&stats1[2 * b + 1], red[1][0]);
    }
}

// ---------------------------------------------------------------------------
// conv_mfma: layers 2-4 (K=4,S=2). 128oc x 64t tile, single-f16 W.
// Input pair-interleaved f16. PAIRED: f16 pair-interleaved out; else fp32.
// ---------------------------------------------------------------------------
template <bool PAIRED>
__global__ __launch_bounds__(256) void conv_mfma(
    const _Float16* __restrict__ x,
    const _Float16* __restrict__ w,
    _Float16* __restrict__ oh, float* __restrict__ oplain,
    float* __restrict__ stats, int Lin, int Lout)
{
    __shared__ _Float16 LW[2][128][40];
    __shared__ _Float16 LX[8][272];
    __shared__ float red[2][256];

    const int tid  = threadIdx.x;
    const int lane = tid & 63, wv = tid >> 6;
    const int m    = lane & 15, quad = lane >> 4;
    const int wv2  = wv >> 1, wvt = wv & 1;
    const int b    = blockIdx.z;
    const int ocb  = blockIdx.y * 128;
    const int t0   = blockIdx.x * 64;

    float4v acc[4][2];
#pragma unroll
    for (int i = 0; i < 4; ++i)
#pragma unroll
        for (int j = 0; j < 2; ++j) acc[i][j] = (float4v){0.f, 0.f, 0.f, 0.f};

    const int lim = (Lin - t0 * 2) * 2;

    for (int ic0 = 0; ic0 < 512; ic0 += 16) {
        __syncthreads();
        // --- stage W: 1024 frag-units
#pragma unroll
        for (int r = 0; r < 4; ++r) {
            const int e = tid + r * 256;
            const int k32l = e >> 9, oc = (e >> 2) & 127, q = e & 3;
            const size_t so = ((size_t)(ocb + oc) * 256 + (ic0 >> 1) + k32l * 4 + q) * 8;
            *(half8v*)&LW[k32l][oc][q * 8] = *(const half8v*)(w + so);
        }
        // --- stage X (copy, 272 16B-units)
        for (int e = tid; e < 272; e += 256) {
            const int pl = e / 34, u = e - pl * 34;
            const _Float16* src = x + ((size_t)(b * 256 + (ic0 >> 1) + pl)) * ((size_t)Lin * 2)
                                   + (size_t)t0 * 4 + (size_t)u * 8;
            half8v val;
            if (u * 8 + 7 < lim) val = *(const half8v*)src;
            else {
#pragma unroll
                for (int k = 0; k < 8; ++k) val[k] = (u * 8 + k < lim) ? src[k] : (_Float16)0.f;
            }
            *(half8v*)&LX[pl][u * 8] = val;
        }
        __syncthreads();
        // --- compute
#pragma unroll
        for (int k32l = 0; k32l < 2; ++k32l) {
            half8v a4[4], bf[2];
#pragma unroll
            for (int i = 0; i < 4; ++i) {
                const int ocl = wv2 * 64 + i * 16 + m;
                a4[i] = *(const half8v*)&LW[k32l][ocl][quad * 8];
            }
#pragma unroll
            for (int j = 0; j < 2; ++j) {
                const int tl = wvt * 32 + j * 16 + m;
                const int pl = k32l * 4 + quad;
                const half4v x0 = *(const half4v*)&LX[pl][tl * 4];
                const half4v x1 = *(const half4v*)&LX[pl][tl * 4 + 4];
                bf[j] = __builtin_shufflevector(x0, x1, 0, 1, 2, 3, 4, 5, 6, 7);
            }
#pragma unroll
            for (int i = 0; i < 4; ++i)
#pragma unroll
                for (int j = 0; j < 2; ++j)
                    acc[i][j] = __builtin_amdgcn_mfma_f32_16x16x32_f16(a4[i], bf[j], acc[i][j], 0, 0, 0);
        }
    }

    // --- epilogue
    float lsum = 0.f, lsq = 0.f;
    uint* ohU = (uint*)oh;
#pragma unroll
    for (int i = 0; i < 4; ++i) {
        const int ocb2 = ocb + wv2 * 64 + i * 16 + quad * 4;
#pragma unroll
        for (int j = 0; j < 2; ++j) {
            const int t = t0 + wvt * 32 + j * 16 + m;
            if (t < Lout) {
                if (PAIRED) {
#pragma unroll
                    for (int pr = 0; pr < 2; ++pr) {
                        const float v0 = acc[i][j][pr * 2], v1 = acc[i][j][pr * 2 + 1];
                        union { uint u; _Float16 h[2]; } pk;
                        pk.h[0] = (_Float16)v0; pk.h[1] = (_Float16)v1;
                        const uint p = (uint)((ocb2 >> 1) + pr);
                        ohU[((size_t)(b * 256 + p)) * Lout + t] = pk.u;
                        lsum += v0 + v1; lsq += v0 * v0 + v1 * v1;
                    }
                } else {
#pragma unroll
                    for (int r = 0; r < 4; ++r) {
                        const float v = acc[i][j][r];
                        oplain[((size_t)(b * 512 + ocb2 + r)) * Lout + t] = v;
                        lsum += v; lsq += v * v;
                    }
                }
            }
        }
    }
    __syncthreads();
    red[0][tid] = lsum; red[1][tid] = lsq;
    __syncthreads();
    for (int s2 = 128; s2 > 0; s2 >>= 1) {
        if (tid < s2) { red[0][tid] += red[0][tid + s2]; red[1][tid] += red[1][tid + s2]; }
        __syncthreads();
    }
    if (tid == 0) {
        atomicAdd(&stats[2 * b], red[0][0]);
        atomicAdd(&stats[2 * b + 1], red[1][0]);
    }
}

// ---------------------------------------------------------------------------
// norm_pair: GN(1grp)+affine+ReLU in place on pair-interleaved f16.
// ---------------------------------------------------------------------------
__global__ __launch_bounds__(256) void norm_pair(
    uint* __restrict__ h, const float* __restrict__ stats,
    const float* __restrict__ gamma, const float* __restrict__ beta,
    int L, float invN)
{
    const int row = blockIdx.y;
    const int b = row >> 8, p = row & 255;
    const int t = blockIdx.x * 256 + threadIdx.x;
    if (t >= L) return;
    const int c0 = 2 * p, c1 = 2 * p + 1;
    const float mu = stats[2 * b] * invN;
    const float var = stats[2 * b + 1] * invN - mu * mu;
    const float rs = rsqrtf(var + 1e-5f);
    const float sc0 = rs * gamma[c0], sh0 = beta[c0] - mu * sc0;
    const float sc1 = rs * gamma[c1], sh1 = beta[c1] - mu * sc1;
    const size_t idx = (size_t)row * L + t;
    union { uint u; _Float16 h2[2]; } pk;
    pk.u = h[idx];
    const float n0 = fmaxf((float)pk.h2[0] * sc0 + sh0, 0.f);
    const float n1 = fmaxf((float)pk.h2[1] * sc1 + sh1, 0.f);
    pk.h2[0] = (_Float16)n0; pk.h2[1] = (_Float16)n1;
    h[idx] = pk.u;
}

// ---------------------------------------------------------------------------
// norm_feat: GN+affine+ReLU on plain fp32 features, in place.
// ---------------------------------------------------------------------------
__global__ __launch_bounds__(256) void norm_feat(
    float* __restrict__ h, const float* __restrict__ stats,
    const float* __restrict__ gamma, const float* __restrict__ beta,
    int L, float invN)
{
    const int row = blockIdx.y;
    const int b = row >> 9, oc = row & 511;
    const int t = blockIdx.x * 256 + threadIdx.x;
    if (t >= L) return;
    const float mu = stats[2 * b] * invN;
    const float var = stats[2 * b + 1] * invN - mu * mu;
    const float rs = rsqrtf(var + 1e-5f);
    const float sc = rs * gamma[oc];
    const float sh = beta[oc] - mu * sc;
    const size_t i = (size_t)row * L + t;
    const float v = h[i] * sc + sh;
    h[i] = v > 0.f ? v : 0.f;
}

// ---------------------------------------------------------------------------
// aa_kernel: row squared-norms of features.
// ---------------------------------------------------------------------------
__global__ __launch_bounds__(256) void aa_kernel(
    const float* __restrict__ fX, const float* __restrict__ fY,
    float* __restrict__ aaX, float* __restrict__ aaY)
{
    const int wave = threadIdx.x >> 6, lane = threadIdx.x & 63;
    const int R = blockIdx.x * 4 + wave;
    const float* f = (R < 8192) ? fX : fY;
    const int r = R & 8191;
    const float* row = f + (size_t)r * 198;
    float s = 0.f;
#pragma unroll
    for (int k = 0; k < 4; ++k) {
        const int j = lane + 64 * k;
        if (j < 198) { const float v = row[j]; s += v * v; }
    }
#pragma unroll
    for (int off = 32; off > 0; off >>= 1) s += __shfl_xor(s, off);
    if (lane == 0) ((R < 8192) ? aaX : aaY)[r] = s;
}

// ---------------------------------------------------------------------------
// cost_kernel: M = f16( min(50 * max(aa[n]+bb[m]-2<p,q>, 0), 65000) ) == 100*C
// ---------------------------------------------------------------------------
__global__ __launch_bounds__(256) void cost_kernel(
    const float* __restrict__ fX, const float* __restrict__ fY,
    const float* __restrict__ aaX, const float* __restrict__ aaY,
    _Float16* __restrict__ Cxy, _Float16* __restrict__ Cxx,
    _Float16* __restrict__ Cyy, _Float16* __restrict__ CTxy)
{
    const int z = blockIdx.z;
    const int mat = z >> 4, b = z & 15;
    const float *P, *Q, *aP, *aQ;
    _Float16 *Cm, *CT = nullptr;
    if (mat == 0) { P = fX; Q = fY; aP = aaX; aQ = aaY; Cm = Cxy; CT = CTxy; }
    else if (mat == 1) { P = fX; Q = fX; aP = aaX; aQ = aaX; Cm = Cxx; }
    else { P = fY; Q = fY; aP = aaY; aQ = aaY; Cm = Cyy; }

    const int n0 = blockIdx.x * 32, m0 = blockIdx.y * 32;
    __shared__ float LP[32][201], LQ[32][201];
    const int tid = threadIdx.x;
    for (int e = tid; e < 32 * 198; e += 256) {
        const int r = e / 198, d = e % 198;
        LP[r][d] = P[((size_t)b * 512 + n0 + r) * 198 + d];
        LQ[r][d] = Q[((size_t)b * 512 + m0 + r) * 198 + d];
    }
    __syncthreads();

    const int tx = tid & 31, ty = tid >> 5;
    float dot[4] = {0.f, 0.f, 0.f, 0.f};
    for (int d = 0; d < 198; ++d) {
        const float qv = LQ[tx][d];
#pragma unroll
        for (int q = 0; q < 4; ++q) dot[q] += LP[ty + 8 * q][d] * qv;
    }
    const int mm = m0 + tx;
    const float bbm = aQ[b * 512 + mm];
#pragma unroll
    for (int q = 0; q < 4; ++q) {
        const int n = n0 + ty + 8 * q;
        float c = 50.f * fmaxf(aP[b * 512 + n] + bbm - 2.f * dot[q], 0.f);  // == 100*C
        c = fminf(c, 65000.f);
        const _Float16 ch = (_Float16)c;
        Cm[((size_t)b * 512 + n) * 512 + mm] = ch;
        if (CT) CT[((size_t)b * 512 + mm) * 512 + n] = ch;
    }
}

// ---------------------------------------------------------------------------
// Per-row half-update (two-pass max-then-sum; same math as proven version).
// dst[p*512+i] = eps*log512 - eps*LSE_j( 400*src[j] - 4*M100[i,j] )
// ---------------------------------------------------------------------------
static __device__ __forceinline__ void sink_rows(
    float* __restrict__ dst, const float* __restrict__ src,
    const _Float16* __restrict__ Mb, int p, int i0, int lane)
{
    const float* sp = src + (size_t)p * 512;
    float s8[8];
    {
        const float4 sa = *(const float4*)&sp[lane * 8];
        const float4 sb = *(const float4*)&sp[lane * 8 + 4];
        s8[0]=sa.x*400.f; s8[1]=sa.y*400.f; s8[2]=sa.z*400.f; s8[3]=sa.w*400.f;
        s8[4]=sb.x*400.f; s8[5]=sb.y*400.f; s8[6]=sb.z*400.f; s8[7]=sb.w*400.f;
    }
#pragma unroll
    for (int rr = 0; rr < 4; ++rr) {
        const int i = i0 + rr;
        const half8v rv = *(const half8v*)(Mb + (size_t)i * 512 + lane * 8);
        float a8[8];
#pragma unroll
        for (int k = 0; k < 8; ++k) a8[k] = fmaf(-4.f, (float)rv[k], s8[k]);
        float mx = a8[0];
#pragma unroll
        for (int k = 1; k < 8; ++k) mx = fmaxf(mx, a8[k]);
        // wave-global max (fmax butterfly, no exps)
#pragma unroll
        for (int off = 32; off > 0; off >>= 1) mx = fmaxf(mx, __shfl_xor(mx, off));
        // sum of exp(a - global max)
        float ss = 0.f;
#pragma unroll
        for (int k = 0; k < 8; ++k) ss += __expf(a8[k] - mx);
#pragma unroll
        for (int off = 32; off > 0; off >>= 1) ss += __shfl_xor(ss, off);
        if (lane == 0)
            dst[(size_t)p * 512 + i] = EPS_LOG512 - EPS_SINK * (mx + logf(ss));
    }
}

// ---------------------------------------------------------------------------
// sink_update: one half-update per launch; grid (32,48), 256 thr.
// ---------------------------------------------------------------------------
__global__ __launch_bounds__(256) void sink_update(
    float* __restrict__ dst, const float* __restrict__ src,
    const _Float16* __restrict__ M0, const _Float16* __restrict__ M1,
    const _Float16* __restrict__ M2)
{
    const int p = blockIdx.y;
    const int mat = p >> 4, b = p & 15;
    const _Float16* M = ((mat == 0) ? M0 : ((mat == 1) ? M1 : M2)) + (size_t)b * 512 * 512;
    const int wave = threadIdx.x >> 6, lane = threadIdx.x & 63;
    const int i0 = blockIdx.x * 16 + wave * 4;
    sink_rows(dst, src, M, p, i0, lane);
}

// ---------------------------------------------------------------------------
__global__ __launch_bounds__(256) void final_kernel(
    const float* __restrict__ f, const float* __restrict__ g,
    float* __restrict__ out)
{
    const int b = blockIdx.x, tid = threadIdx.x;
    __shared__ float red[256];
    float a = 0.f;
    for (int n = tid; n < 512; n += 256) {
        const float xy = f[(0 * 16 + b) * 512 + n] + g[(0 * 16 + b) * 512 + n];
        const float xx = f[(1 * 16 + b) * 512 + n] + g[(1 * 16 + b) * 512 + n];
        const float yy = f[(2 * 16 + b) * 512 + n] + g[(2 * 16 + b) * 512 + n];
        a += xy - 0.5f * (xx + yy);
    }
    red[tid] = a;
    __syncthreads();
    for (int s2 = 128; s2 > 0; s2 >>= 1) {
        if (tid < s2) red[tid] += red[tid + s2];
        __syncthreads();
    }
    if (tid == 0) out[b] = red[0] * (1.0f / 512.0f);
}

// ---------------------------------------------------------------------------
extern "C" void kernel_launch(void* const* d_in, const int* in_sizes, int n_in,
                              void* d_out, int out_size, void* d_ws, size_t ws_size,
                              hipStream_t stream)
{
    (void)in_sizes; (void)n_in; (void)out_size; (void)ws_size;
    char* ws = (char*)d_ws;
    const float* yhat = (const float*)d_in[0];
    const float* ysig = (const float*)d_in[1];
    const float* Wl[5]; const float* gl[5]; const float* bl[5];
    for (int i = 0; i < 5; ++i) {
        Wl[i] = (const float*)d_in[2 + 3 * i];
        gl[i] = (const float*)d_in[3 + 3 * i];
        bl[i] = (const float*)d_in[4 + 3 * i];
    }
    float* out = (float*)d_out;
    float* statsA = (float*)(ws + O_STATS);

    _Float16* w1 = (_Float16*)(ws + O_W1);
    _Float16* w2 = (_Float16*)(ws + O_W2);
    _Float16* w3 = (_Float16*)(ws + O_W3);
    _Float16* w4 = (_Float16*)(ws + O_W4);
    _Float16* h0 = (_Float16*)(ws + O_H0);
    _Float16* h1 = (_Float16*)(ws + O_H1);
    _Float16* h2 = (_Float16*)(ws + O_H2);
    _Float16* h3 = (_Float16*)(ws + O_H3);

    hipMemsetAsync(statsA, 0, 512 * sizeof(float), stream);
    prep_w<<<dim3(1024, 4), 256, 0, stream>>>(Wl[1], Wl[2], Wl[3], Wl[4],
        w1, w2, w3, w4);

    for (int s = 0; s < 2; ++s) {
        const float* wav = (s == 0) ? yhat : ysig;
        float* st = statsA + (size_t)s * 160;
        float* ft = (float*)(ws + ((s == 0) ? O_FEATX : O_FEATY));

        conv0_store<<<dim3(25, 16), 256, 0, stream>>>(wav, Wl[0], h0, st);
        norm_h0<<<dim3(4, 8192), 256, 0, stream>>>(h0, st, gl[0], bl[0]);

        conv1_mfma<<<dim3(13, 4, 16), 256, 0, stream>>>(
            h0, w1, h1, st + 32);
        norm_pair<<<dim3(7, 4096), 256, 0, stream>>>(
            (uint*)h1, st + 32, gl[1], bl[1], 1598, 1.f / (512.f * 1598.f));

        conv_mfma<true><<<dim3(13, 4, 16), 256, 0, stream>>>(
            h1, w2, h2, nullptr, st + 64, 1598, 798);
        norm_pair<<<dim3(4, 4096), 256, 0, stream>>>(
            (uint*)h2, st + 64, gl[2], bl[2], 798, 1.f / (512.f * 798.f));

        conv_mfma<true><<<dim3(7, 4, 16), 256, 0, stream>>>(
            h2, w3, h3, nullptr, st + 96, 798, 398);
        norm_pair<<<dim3(2, 4096), 256, 0, stream>>>(
            (uint*)h3, st + 96, gl[3], bl[3], 398, 1.f / (512.f * 398.f));

        conv_mfma<false><<<dim3(4, 4, 16), 256, 0, stream>>>(
            h3, w4, nullptr, ft, st + 128, 398, 198);
        norm_feat<<<dim3(1, 8192), 256, 0, stream>>>(
            ft, st + 128, gl[4], bl[4], 198, 1.f / (512.f * 198.f));
    }

    float* featX = (float*)(ws + O_FEATX);
    float* featY = (float*)(ws + O_FEATY);
    aa_kernel<<<4096, 256, 0, stream>>>(featX, featY, (float*)(ws + O_AAX), (float*)(ws + O_AAY));
    cost_kernel<<<dim3(16, 16, 48), 256, 0, stream>>>(
        featX, featY, (float*)(ws + O_AAX), (float*)(ws + O_AAY),
        (_Float16*)(ws + O_CXY), (_Float16*)(ws + O_CXX), (_Float16*)(ws + O_CYY),
        (_Float16*)(ws + O_CTXY));

    hipMemsetAsync(ws + O_F, 0, 2 * 24576 * sizeof(float), stream);

    float* fptr = (float*)(ws + O_F);
    float* gptr = (float*)(ws + O_G);
    _Float16* cxy  = (_Float16*)(ws + O_CXY);
    _Float16* ctxy = (_Float16*)(ws + O_CTXY);
    _Float16* cxx  = (_Float16*)(ws + O_CXX);
    _Float16* cyy  = (_Float16*)(ws + O_CYY);

    for (int it = 0; it < 50; ++it) {
        sink_update<<<dim3(32, 48), 256, 0, stream>>>(gptr, fptr, ctxy, cxx, cyy);
        sink_update<<<dim3(32, 48), 256, 0, stream>>>(fptr, gptr, cxy, cxx, cyy);
    }

    final_kernel<<<16, 256, 0, stream>>>(fptr, gptr, out);
}